// Round 7
// baseline (155.492 us; speedup 1.0000x reference)
//
#include <hip/hip_runtime.h>

// Round 7: T2 LDS XOR-swizzle (byte ^= (row&7)<<4) on ALL MFMA operand tiles,
// applied both-sides (pre-swizzled global source for global_load_lds stages,
// swizzled dest for VALU-written A tiles, swizzled ds_reads). k_gin retiled
// to 64x256 (32 MFMA/wave/barrier, 2 blocks/CU) and reads fp32 X directly
// (cast kernel is now W-only). Double-buffered 2-deep pipeline kept.

#define E_DIM 1024

typedef short bf16x8 __attribute__((ext_vector_type(8)));
typedef float f32x4  __attribute__((ext_vector_type(4)));

__device__ inline unsigned short f2bf(float f) {
    unsigned u = __builtin_bit_cast(unsigned, f);
    u = (u + 0x7FFFu + ((u >> 16) & 1u)) >> 16;   // RNE; inputs finite
    return (unsigned short)u;
}

__device__ inline void gload_lds16(const void* g, void* l) {
    __builtin_amdgcn_global_load_lds(
        (const __attribute__((address_space(1))) unsigned int*)g,
        (__attribute__((address_space(3))) unsigned int*)l, 16, 0, 0);
}

// XOR swizzle within each 8-row stripe of a 128B-stride tile (involution).
__device__ inline int swzb(int row, int colbyte) {
    return colbyte ^ ((row & 7) << 4);
}

// ---------------------------------------------------------------------------
// Kernel 0: cast weights only: Wi (3M) then Wo (1M) fp32 -> bf16.
// ---------------------------------------------------------------------------
__global__ __launch_bounds__(256) void k_castw(
    const float* __restrict__ w_in, const float* __restrict__ w_out,
    unsigned short* __restrict__ dst)
{
    const int id8 = blockIdx.x * 256 + threadIdx.x;   // 524288 float8 units
    const int WI8 = 3 * E_DIM * E_DIM / 8;            // 393216
    const float* src = (id8 < WI8) ? (w_in + (size_t)id8 * 8)
                                   : (w_out + (size_t)(id8 - WI8) * 8);
    float4 f0 = *reinterpret_cast<const float4*>(src);
    float4 f1 = *reinterpret_cast<const float4*>(src + 4);
    ushort4 o0, o1;
    o0.x = f2bf(f0.x); o0.y = f2bf(f0.y); o0.z = f2bf(f0.z); o0.w = f2bf(f0.w);
    o1.x = f2bf(f1.x); o1.y = f2bf(f1.y); o1.z = f2bf(f1.z); o1.w = f2bf(f1.w);
    *reinterpret_cast<ushort4*>(dst + (size_t)id8 * 8)     = o0;
    *reinterpret_cast<ushort4*>(dst + (size_t)id8 * 8 + 4) = o1;
}

// ---------------------------------------------------------------------------
// Kernel 1: in-projection GEMM, 64x256 tile, BK=64, 4 waves (2x2, each 32x128),
// double-buffered, one barrier/K-step. A read as fp32 (reg cvt -> swizzled LDS
// write); W bf16 via global_load_lds with pre-swizzled source. Grid 384,
// XCD-chunked (48/XCD; within a chunk y-major so the W n-tile stays L2-hot).
// Epilogue: z=0 Q natural [b][t][e]; z=1 K natural; z=2 V transposed [b][e][t].
// ---------------------------------------------------------------------------
__global__ __launch_bounds__(256) void k_gin(
    const float* __restrict__ q_in, const float* __restrict__ k_in,
    const float* __restrict__ v_in, const unsigned short* __restrict__ Wibf,
    const float* __restrict__ b_in,
    unsigned short* __restrict__ qslab, unsigned short* __restrict__ kslab,
    unsigned short* __restrict__ vtb)
{
    const int i = blockIdx.x;
    const int tile = (i & 7) * 48 + (i >> 3);     // 384 = 8 XCD * 48
    const int z = tile >> 7;                      // 0..2
    const int rem = tile & 127;
    const int x = rem >> 5, y = rem & 31;         // x: n-tile, y: m-tile

    const float* X = (z == 0) ? q_in : (z == 1 ? k_in : v_in);
    const unsigned short* W = Wibf + (size_t)z * 1048576;
    const float* bz = b_in + z * E_DIM;

    const int nBase = x * 256;
    const int mBase = y * 64;                     // b-major row space
    const int b = mBase >> 10, tBase = mBase & 1023;

    __shared__ short As[2][64 * 64];              // 2 x 8 KB
    __shared__ short Bs[2][256 * 64];             // 2 x 32 KB  (total 80 KB)

    const int tid = threadIdx.x;
    const int lane = tid & 63, wave = tid >> 6;
    const int wr = wave >> 1, wc = wave & 1;
    const int l15 = lane & 15, l4 = lane >> 4;

    auto stage = [&](int bufI, int k0) {
        // B: 256x64 bf16, linear LDS dest + swizzled global source
        #pragma unroll
        for (int l = 0; l < 8; ++l) {
            int off = l * 4096 + tid * 16;
            int row = off >> 7, cb = off & 127;
            gload_lds16((const char*)W + ((size_t)(nBase + row) * E_DIM + k0) * 2
                            + swzb(row, cb),
                        (char*)&Bs[bufI][0] + off);
        }
        // A: 64x64 fp32 -> bf16, swizzled LDS dest (logical global read)
        #pragma unroll
        for (int l = 0; l < 2; ++l) {
            int u = tid + 256 * l;                // 512 bf16x8 units
            int row = u >> 3, cslot = u & 7;      // 16B slots
            const float* src = &X[(size_t)((tBase + row) * 2 + b) * E_DIM
                                  + k0 + cslot * 8];
            float4 f0 = *reinterpret_cast<const float4*>(src);
            float4 f1 = *reinterpret_cast<const float4*>(src + 4);
            bf16x8 p;
            p[0] = (short)f2bf(f0.x); p[1] = (short)f2bf(f0.y);
            p[2] = (short)f2bf(f0.z); p[3] = (short)f2bf(f0.w);
            p[4] = (short)f2bf(f1.x); p[5] = (short)f2bf(f1.y);
            p[6] = (short)f2bf(f1.z); p[7] = (short)f2bf(f1.w);
            *reinterpret_cast<bf16x8*>(
                &As[bufI][row * 64 + (swzb(row, cslot * 16) >> 1)]) = p;
        }
    };

    f32x4 acc[2][8] = {};

    stage(0, 0);
    __syncthreads();
    int cur = 0;
    for (int it = 0; it < 16; ++it) {
        if (it < 15) stage(cur ^ 1, (it + 1) * 64);
        #pragma unroll
        for (int kk = 0; kk < 64; kk += 32) {
            bf16x8 af[2], bfr[8];
            #pragma unroll
            for (int ii = 0; ii < 2; ++ii) {
                int row = wr * 32 + ii * 16 + l15;
                af[ii] = *reinterpret_cast<const bf16x8*>(
                    &As[cur][row * 64 + (swzb(row, (kk + l4 * 8) * 2) >> 1)]);
            }
            #pragma unroll
            for (int j = 0; j < 8; ++j) {
                int row = wc * 128 + j * 16 + l15;
                bfr[j] = *reinterpret_cast<const bf16x8*>(
                    &Bs[cur][row * 64 + (swzb(row, (kk + l4 * 8) * 2) >> 1)]);
            }
            #pragma unroll
            for (int ii = 0; ii < 2; ++ii)
                #pragma unroll
                for (int j = 0; j < 8; ++j)
                    acc[ii][j] = __builtin_amdgcn_mfma_f32_16x16x32_bf16(
                        af[ii], bfr[j], acc[ii][j], 0, 0, 0);
        }
        __syncthreads();
        cur ^= 1;
    }

    #pragma unroll
    for (int ii = 0; ii < 2; ++ii) {
        int t0 = tBase + wr * 32 + ii * 16 + l4 * 4;
        #pragma unroll
        for (int j = 0; j < 8; ++j) {
            int col = nBase + wc * 128 + j * 16 + l15;
            float bv = bz[col];
            unsigned short v4[4];
            #pragma unroll
            for (int q = 0; q < 4; ++q) v4[q] = f2bf(acc[ii][j][q] + bv);
            if (z == 0) {
                #pragma unroll
                for (int q = 0; q < 4; ++q)
                    qslab[(size_t)b * 1048576 + (size_t)(t0 + q) * E_DIM + col] = v4[q];
            } else if (z == 1) {
                #pragma unroll
                for (int q = 0; q < 4; ++q)
                    kslab[(size_t)b * 1048576 + (size_t)(t0 + q) * E_DIM + col] = v4[q];
            } else {
                ushort4 w = {v4[0], v4[1], v4[2], v4[3]};
                *reinterpret_cast<ushort4*>(
                    &vtb[((size_t)b * 1024 + col) * 1024 + t0]) = w;
            }
        }
    }
}

// ---------------------------------------------------------------------------
// Kernel 2: direct masked linear attention, swizzled LDS, K/V double-buffered.
// Per block (bh, qtile): O = 0.125 * sum_{c<=qt} mask_if_diag(Q Kc^T) Vc.
// Grid 512, XCD-chunked; complementary qt pairing balances the triangle.
// ---------------------------------------------------------------------------
__global__ __launch_bounds__(256) void k_attn(
    const unsigned short* __restrict__ qslab, const unsigned short* __restrict__ kslab,
    const unsigned short* __restrict__ vtb, unsigned short* __restrict__ attnbf)
{
    const int i = blockIdx.x;
    const int xcd = i & 7, u = i >> 3;            // u in 0..63
    const int bh = xcd * 4 + (u >> 4);
    const int qtr = u & 15;
    const int qt = ((u >> 5) & 1) ? (15 - qtr) : qtr;
    const int b = bh >> 4, h = bh & 15;
    const int colb = h * 64, t0q = qt * 64;

    __shared__ short Qs[64 * 64];
    __shared__ short Ks[2][64 * 64];
    __shared__ short Vts[2][64 * 64];
    __shared__ short Ss[64 * 72];                 // padded (VALU-written)

    const int tid = threadIdx.x;
    const int lane = tid & 63, wave = tid >> 6;
    const int wr = wave >> 1, wc = wave & 1;
    const int l15 = lane & 15, l4 = lane >> 4;

    auto stageKV = [&](int bufI, int c) {
        int t0k = c * 64;
        #pragma unroll
        for (int l = 0; l < 2; ++l) {
            int off = l * 4096 + tid * 16;
            int row = off >> 7, cb = off & 127;
            int scb = swzb(row, cb);
            gload_lds16((const char*)kslab +
                            ((size_t)b * 1048576 + (size_t)(t0k + row) * E_DIM + colb) * 2 + scb,
                        (char*)&Ks[bufI][0] + off);
            gload_lds16((const char*)vtb +
                            (((size_t)(b * 1024 + colb + row)) * 1024 + t0k) * 2 + scb,
                        (char*)&Vts[bufI][0] + off);
        }
    };

    #pragma unroll
    for (int l = 0; l < 2; ++l) {                 // stage Q once (swizzled src)
        int off = l * 4096 + tid * 16;
        int row = off >> 7, cb = off & 127;
        gload_lds16((const char*)qslab +
                        ((size_t)b * 1048576 + (size_t)(t0q + row) * E_DIM + colb) * 2
                        + swzb(row, cb),
                    (char*)Qs + off);
    }
    stageKV(0, 0);
    __syncthreads();

    f32x4 oacc[2][2] = {};
    int cur = 0;

    for (int c = 0; c <= qt; ++c) {
        if (c < qt) stageKV(cur ^ 1, c + 1);      // prefetch next K/V tile

        // S = Q Kc^T
        f32x4 sacc[2][2] = {};
        #pragma unroll
        for (int kk = 0; kk < 64; kk += 32) {
            bf16x8 af[2], bfr[2];
            #pragma unroll
            for (int ii = 0; ii < 2; ++ii) {
                int row = wr * 32 + ii * 16 + l15;
                af[ii] = *reinterpret_cast<const bf16x8*>(
                    &Qs[row * 64 + (swzb(row, (kk + l4 * 8) * 2) >> 1)]);
            }
            #pragma unroll
            for (int j = 0; j < 2; ++j) {
                int row = wc * 32 + j * 16 + l15;
                bfr[j] = *reinterpret_cast<const bf16x8*>(
                    &Ks[cur][row * 64 + (swzb(row, (kk + l4 * 8) * 2) >> 1)]);
            }
            #pragma unroll
            for (int ii = 0; ii < 2; ++ii)
                #pragma unroll
                for (int j = 0; j < 2; ++j)
                    sacc[ii][j] = __builtin_amdgcn_mfma_f32_16x16x32_bf16(
                        af[ii], bfr[j], sacc[ii][j], 0, 0, 0);
        }
        // mask (diagonal tile only) + cvt -> Ss
        const bool diag = (c == qt);
        #pragma unroll
        for (int ii = 0; ii < 2; ++ii) {
            #pragma unroll
            for (int j = 0; j < 2; ++j) {
                int kr = wc * 32 + j * 16 + l15;
                #pragma unroll
                for (int q = 0; q < 4; ++q) {
                    int qr = wr * 32 + ii * 16 + l4 * 4 + q;
                    short sv = (short)f2bf(sacc[ii][j][q]);
                    Ss[qr * 72 + kr] = (!diag || kr <= qr) ? sv : (short)0;
                }
            }
        }
        __syncthreads();

        // O += S Vc
        #pragma unroll
        for (int kk = 0; kk < 64; kk += 32) {
            bf16x8 af[2], bfr[2];
            #pragma unroll
            for (int ii = 0; ii < 2; ++ii)
                af[ii] = *reinterpret_cast<const bf16x8*>(
                            &Ss[(wr * 32 + ii * 16 + l15) * 72 + kk + l4 * 8]);
            #pragma unroll
            for (int j = 0; j < 2; ++j) {
                int row = wc * 32 + j * 16 + l15;
                bfr[j] = *reinterpret_cast<const bf16x8*>(
                    &Vts[cur][row * 64 + (swzb(row, (kk + l4 * 8) * 2) >> 1)]);
            }
            #pragma unroll
            for (int ii = 0; ii < 2; ++ii)
                #pragma unroll
                for (int j = 0; j < 2; ++j)
                    oacc[ii][j] = __builtin_amdgcn_mfma_f32_16x16x32_bf16(
                        af[ii], bfr[j], oacc[ii][j], 0, 0, 0);
        }
        __syncthreads();
        cur ^= 1;
    }

    #pragma unroll
    for (int ii = 0; ii < 2; ++ii) {
        #pragma unroll
        for (int j = 0; j < 2; ++j) {
            int dv = wc * 32 + j * 16 + l15;
            #pragma unroll
            for (int q = 0; q < 4; ++q) {
                int qr = wr * 32 + ii * 16 + l4 * 4 + q;
                attnbf[(size_t)b * 1048576 + (size_t)(t0q + qr) * E_DIM + colb + dv] =
                    f2bf(oacc[ii][j][q] * 0.125f);
            }
        }
    }
}

// ---------------------------------------------------------------------------
// Kernel 3: out-projection GEMM, 64x64 tile, swizzled LDS, double-buffered.
// Grid 512 XCD-chunked. fp32 output rows r = t*2+b.
// ---------------------------------------------------------------------------
__global__ __launch_bounds__(256) void k_gout(
    const unsigned short* __restrict__ attnbf, const unsigned short* __restrict__ Wobf,
    const float* __restrict__ bias, float* __restrict__ out)
{
    const int i = blockIdx.x;
    const int tile = (i & 7) * 64 + (i >> 3);     // 512 = 8 * 64
    const int x = tile & 15, y = tile >> 4;
    const int nBase = x * 64;
    const int mBase = y * 64;                     // r-space (t*2+b)

    __shared__ short As[2][64 * 64];
    __shared__ short Bs[2][64 * 64];

    const int tid = threadIdx.x;
    const int lane = tid & 63, wave = tid >> 6;
    const int wr = wave >> 1, wc = wave & 1;
    const int l15 = lane & 15, l4 = lane >> 4;

    auto stage = [&](int bufI, int k0) {
        #pragma unroll
        for (int l = 0; l < 2; ++l) {
            int off = l * 4096 + tid * 16;
            int row = off >> 7, cb = off & 127;
            int scb = swzb(row, cb);
            gload_lds16((const char*)Wobf + ((size_t)(nBase + row) * E_DIM + k0) * 2 + scb,
                        (char*)&Bs[bufI][0] + off);
            int r = mBase + row, t = r >> 1, bb = r & 1;
            gload_lds16((const char*)attnbf +
                            ((size_t)bb * 1048576 + (size_t)t * E_DIM + k0) * 2 + scb,
                        (char*)&As[bufI][0] + off);
        }
    };

    f32x4 acc[2][2] = {};

    stage(0, 0);
    __syncthreads();
    int cur = 0;
    for (int it = 0; it < 16; ++it) {
        if (it < 15) stage(cur ^ 1, (it + 1) * 64);
        #pragma unroll
        for (int kk = 0; kk < 64; kk += 32) {
            bf16x8 af[2], bfr[2];
            #pragma unroll
            for (int ii = 0; ii < 2; ++ii) {
                int row = wr * 32 + ii * 16 + l15;
                af[ii] = *reinterpret_cast<const bf16x8*>(
                    &As[cur][row * 64 + (swzb(row, (kk + l4 * 8) * 2) >> 1)]);
            }
            #pragma unroll
            for (int j = 0; j < 2; ++j) {
                int row = wc * 32 + j * 16 + l15;
                bfr[j] = *reinterpret_cast<const bf16x8*>(
                    &Bs[cur][row * 64 + (swzb(row, (kk + l4 * 8) * 2) >> 1)]);
            }
            #pragma unroll
            for (int ii = 0; ii < 2; ++ii)
                #pragma unroll
                for (int j = 0; j < 2; ++j)
                    acc[ii][j] = __builtin_amdgcn_mfma_f32_16x16x32_bf16(
                        af[ii], bfr[j], acc[ii][j], 0, 0, 0);
        }
        __syncthreads();
        cur ^= 1;
    }

    #pragma unroll
    for (int ii = 0; ii < 2; ++ii) {
        int r0 = mBase + wr * 32 + ii * 16 + l4 * 4;
        #pragma unroll
        for (int j = 0; j < 2; ++j) {
            int col = nBase + wc * 32 + j * 16 + l15;
            float bv = bias[col];
            #pragma unroll
            for (int q = 0; q < 4; ++q)
                out[(size_t)(r0 + q) * E_DIM + col] = acc[ii][j][q] + bv;
        }
    }
}

// ---------------------------------------------------------------------------
extern "C" void kernel_launch(void* const* d_in, const int* in_sizes, int n_in,
                              void* d_out, int out_size, void* d_ws, size_t ws_size,
                              hipStream_t stream)
{
    const float* q_in  = (const float*)d_in[0];
    const float* k_in  = (const float*)d_in[1];
    const float* v_in  = (const float*)d_in[2];
    const float* w_in  = (const float*)d_in[3];
    const float* b_in  = (const float*)d_in[4];
    const float* w_out = (const float*)d_in[5];
    const float* b_out = (const float*)d_in[6];

    // ws layout (24 MiB):
    //   [ 0, 6M) Wibf bf16   [ 6M, 8M) Wobf bf16
    //   [ 8M,12M) qslab bf16 [b][t][e]   [12M,16M) kslab bf16 [b][t][e]
    //   [16M,20M) vtb bf16 [b][e][t]     [20M,24M) attnbf bf16 [b][t][e]
    char* w = (char*)d_ws;
    unsigned short* Wibf   = (unsigned short*)w;
    unsigned short* Wobf   = (unsigned short*)(w + 6291456);
    unsigned short* qslab  = (unsigned short*)(w + 8388608);
    unsigned short* kslab  = (unsigned short*)(w + 12582912);
    unsigned short* vtb    = (unsigned short*)(w + 16777216);
    unsigned short* attnbf = (unsigned short*)(w + 20971520);
    float* outp = (float*)d_out;

    k_castw<<<2048, 256, 0, stream>>>(w_in, w_out, Wibf);
    k_gin<<<384, 256, 0, stream>>>(q_in, k_in, v_in, Wibf, b_in, qslab, kslab, vtb);
    k_attn<<<512, 256, 0, stream>>>(qslab, kslab, vtb, attnbf);
    k_gout<<<512, 256, 0, stream>>>(attnbf, Wobf, b_out, outp);
}

// Round 8
// 147.864 us; speedup vs baseline: 1.0516x; 1.0516x over previous
//
#include <hip/hip_runtime.h>

// Round 8: attention restructured to chunked-prefix-in-kernel:
//   P = sum_{c<qt} Kc^T Vc accumulated in fp32 regs (1 GEMM + 1 barrier per
//   c-step, operands Kt/Vt), then O = Q@P + masked-diag(Q Kqt^T)@Vqt.
//   ~38% less MFMA work and ~40% fewer barriers than the direct form.
// gin re-emits ktb (transposed K) for P's A-operand. gin/gout/castw kept
// from round 7 (swizzled LDS, 2-phase dbuf, XCD-chunked).

#define E_DIM 1024

typedef short bf16x8 __attribute__((ext_vector_type(8)));
typedef float f32x4  __attribute__((ext_vector_type(4)));

__device__ inline unsigned short f2bf(float f) {
    unsigned u = __builtin_bit_cast(unsigned, f);
    u = (u + 0x7FFFu + ((u >> 16) & 1u)) >> 16;   // RNE; inputs finite
    return (unsigned short)u;
}

__device__ inline void gload_lds16(const void* g, void* l) {
    __builtin_amdgcn_global_load_lds(
        (const __attribute__((address_space(1))) unsigned int*)g,
        (__attribute__((address_space(3))) unsigned int*)l, 16, 0, 0);
}

// XOR swizzle within each 8-row stripe of a 128B-stride tile (involution).
__device__ inline int swzb(int row, int colbyte) {
    return colbyte ^ ((row & 7) << 4);
}

// ---------------------------------------------------------------------------
// Kernel 0: cast weights only: Wi (3M) then Wo (1M) fp32 -> bf16.
// ---------------------------------------------------------------------------
__global__ __launch_bounds__(256) void k_castw(
    const float* __restrict__ w_in, const float* __restrict__ w_out,
    unsigned short* __restrict__ dst)
{
    const int id8 = blockIdx.x * 256 + threadIdx.x;   // 524288 float8 units
    const int WI8 = 3 * E_DIM * E_DIM / 8;            // 393216
    const float* src = (id8 < WI8) ? (w_in + (size_t)id8 * 8)
                                   : (w_out + (size_t)(id8 - WI8) * 8);
    float4 f0 = *reinterpret_cast<const float4*>(src);
    float4 f1 = *reinterpret_cast<const float4*>(src + 4);
    ushort4 o0, o1;
    o0.x = f2bf(f0.x); o0.y = f2bf(f0.y); o0.z = f2bf(f0.z); o0.w = f2bf(f0.w);
    o1.x = f2bf(f1.x); o1.y = f2bf(f1.y); o1.z = f2bf(f1.z); o1.w = f2bf(f1.w);
    *reinterpret_cast<ushort4*>(dst + (size_t)id8 * 8)     = o0;
    *reinterpret_cast<ushort4*>(dst + (size_t)id8 * 8 + 4) = o1;
}

// ---------------------------------------------------------------------------
// Kernel 1: in-projection GEMM, 64x256 tile, BK=64, double-buffered,
// one barrier/K-step. A fp32 reg-cvt -> swizzled LDS; W bf16 gload_lds with
// pre-swizzled source. Grid 384 XCD-chunked.
// Epilogue: z=0 Q natural; z=1 K natural + Kt; z=2 Vt only.
// ---------------------------------------------------------------------------
__global__ __launch_bounds__(256) void k_gin(
    const float* __restrict__ q_in, const float* __restrict__ k_in,
    const float* __restrict__ v_in, const unsigned short* __restrict__ Wibf,
    const float* __restrict__ b_in,
    unsigned short* __restrict__ qslab, unsigned short* __restrict__ kslab,
    unsigned short* __restrict__ ktb,   unsigned short* __restrict__ vtb)
{
    const int i = blockIdx.x;
    const int tile = (i & 7) * 48 + (i >> 3);     // 384 = 8 XCD * 48
    const int z = tile >> 7;                      // 0..2
    const int rem = tile & 127;
    const int x = rem >> 5, y = rem & 31;         // x: n-tile, y: m-tile

    const float* X = (z == 0) ? q_in : (z == 1 ? k_in : v_in);
    const unsigned short* W = Wibf + (size_t)z * 1048576;
    const float* bz = b_in + z * E_DIM;

    const int nBase = x * 256;
    const int mBase = y * 64;                     // b-major row space
    const int b = mBase >> 10, tBase = mBase & 1023;

    __shared__ short As[2][64 * 64];              // 2 x 8 KB
    __shared__ short Bs[2][256 * 64];             // 2 x 32 KB

    const int tid = threadIdx.x;
    const int lane = tid & 63, wave = tid >> 6;
    const int wr = wave >> 1, wc = wave & 1;
    const int l15 = lane & 15, l4 = lane >> 4;

    auto stage = [&](int bufI, int k0) {
        #pragma unroll
        for (int l = 0; l < 8; ++l) {             // B: 256x64 bf16
            int off = l * 4096 + tid * 16;
            int row = off >> 7, cb = off & 127;
            gload_lds16((const char*)W + ((size_t)(nBase + row) * E_DIM + k0) * 2
                            + swzb(row, cb),
                        (char*)&Bs[bufI][0] + off);
        }
        #pragma unroll
        for (int l = 0; l < 2; ++l) {             // A: 64x64 fp32 -> bf16
            int u = tid + 256 * l;
            int row = u >> 3, cslot = u & 7;
            const float* src = &X[(size_t)((tBase + row) * 2 + b) * E_DIM
                                  + k0 + cslot * 8];
            float4 f0 = *reinterpret_cast<const float4*>(src);
            float4 f1 = *reinterpret_cast<const float4*>(src + 4);
            bf16x8 p;
            p[0] = (short)f2bf(f0.x); p[1] = (short)f2bf(f0.y);
            p[2] = (short)f2bf(f0.z); p[3] = (short)f2bf(f0.w);
            p[4] = (short)f2bf(f1.x); p[5] = (short)f2bf(f1.y);
            p[6] = (short)f2bf(f1.z); p[7] = (short)f2bf(f1.w);
            *reinterpret_cast<bf16x8*>(
                &As[bufI][row * 64 + (swzb(row, cslot * 16) >> 1)]) = p;
        }
    };

    f32x4 acc[2][8] = {};

    stage(0, 0);
    __syncthreads();
    int cur = 0;
    for (int it = 0; it < 16; ++it) {
        if (it < 15) stage(cur ^ 1, (it + 1) * 64);
        #pragma unroll
        for (int kk = 0; kk < 64; kk += 32) {
            bf16x8 af[2], bfr[8];
            #pragma unroll
            for (int ii = 0; ii < 2; ++ii) {
                int row = wr * 32 + ii * 16 + l15;
                af[ii] = *reinterpret_cast<const bf16x8*>(
                    &As[cur][row * 64 + (swzb(row, (kk + l4 * 8) * 2) >> 1)]);
            }
            #pragma unroll
            for (int j = 0; j < 8; ++j) {
                int row = wc * 128 + j * 16 + l15;
                bfr[j] = *reinterpret_cast<const bf16x8*>(
                    &Bs[cur][row * 64 + (swzb(row, (kk + l4 * 8) * 2) >> 1)]);
            }
            #pragma unroll
            for (int ii = 0; ii < 2; ++ii)
                #pragma unroll
                for (int j = 0; j < 8; ++j)
                    acc[ii][j] = __builtin_amdgcn_mfma_f32_16x16x32_bf16(
                        af[ii], bfr[j], acc[ii][j], 0, 0, 0);
        }
        __syncthreads();
        cur ^= 1;
    }

    #pragma unroll
    for (int ii = 0; ii < 2; ++ii) {
        int t0 = tBase + wr * 32 + ii * 16 + l4 * 4;
        #pragma unroll
        for (int j = 0; j < 8; ++j) {
            int col = nBase + wc * 128 + j * 16 + l15;
            float bv = bz[col];
            unsigned short v4[4];
            #pragma unroll
            for (int q = 0; q < 4; ++q) v4[q] = f2bf(acc[ii][j][q] + bv);
            if (z == 0) {
                #pragma unroll
                for (int q = 0; q < 4; ++q)
                    qslab[(size_t)b * 1048576 + (size_t)(t0 + q) * E_DIM + col] = v4[q];
            } else if (z == 1) {
                #pragma unroll
                for (int q = 0; q < 4; ++q)
                    kslab[(size_t)b * 1048576 + (size_t)(t0 + q) * E_DIM + col] = v4[q];
                ushort4 w = {v4[0], v4[1], v4[2], v4[3]};
                *reinterpret_cast<ushort4*>(
                    &ktb[((size_t)b * 1024 + col) * 1024 + t0]) = w;
            } else {
                ushort4 w = {v4[0], v4[1], v4[2], v4[3]};
                *reinterpret_cast<ushort4*>(
                    &vtb[((size_t)b * 1024 + col) * 1024 + t0]) = w;
            }
        }
    }
}

// ---------------------------------------------------------------------------
// Kernel 2: chunked-prefix linear attention in one kernel.
// Per block (bh, qt):
//   P[dk][dv] = sum_{c<qt} Kt_c . Vt_c   (fp32 acc, 1 GEMM + 1 barrier / c)
//   O = Q @ P  +  tril(Q Kqt^T) @ Vqt ;  attn = 0.125 * O  (bf16)
// Grid 512, XCD-chunked (4 bh/XCD -> K/V L2-hot); complementary qt pairing.
// ---------------------------------------------------------------------------
__global__ __launch_bounds__(256) void k_attn(
    const unsigned short* __restrict__ qslab, const unsigned short* __restrict__ kslab,
    const unsigned short* __restrict__ ktb,  const unsigned short* __restrict__ vtb,
    unsigned short* __restrict__ attnbf)
{
    const int i = blockIdx.x;
    const int xcd = i & 7, u = i >> 3;            // u in 0..63
    const int bh = xcd * 4 + (u >> 4);
    const int qtr = u & 15;
    const int qt = ((u >> 5) & 1) ? (15 - qtr) : qtr;
    const int b = bh >> 4, h = bh & 15;
    const int colb = h * 64, t0q = qt * 64;

    __shared__ short Qs[64 * 64];
    __shared__ short KB[2][64 * 64];              // Kt tiles / diag K natural
    __shared__ short VB[2][64 * 64];              // Vt tiles
    __shared__ short Ss[64 * 72];                 // masked S (padded)
    __shared__ short PTs[64 * 72];                // P^T bf16 (padded)

    const int tid = threadIdx.x;
    const int lane = tid & 63, wave = tid >> 6;
    const int wr = wave >> 1, wc = wave & 1;
    const int l15 = lane & 15, l4 = lane >> 4;

    // stage Kt_c and Vt_c (both transposed slabs, rows = head dims)
    auto stageP = [&](int bufI, int c) {
        int t0k = c * 64;
        #pragma unroll
        for (int l = 0; l < 2; ++l) {
            int off = l * 4096 + tid * 16;
            int row = off >> 7, cb = off & 127;
            int scb = swzb(row, cb);
            size_t trn = ((size_t)(b * 1024 + colb + row)) * 1024 + t0k;
            gload_lds16((const char*)ktb + trn * 2 + scb, (char*)&KB[bufI][0] + off);
            gload_lds16((const char*)vtb + trn * 2 + scb, (char*)&VB[bufI][0] + off);
        }
    };
    // stage diagonal tiles: K natural rows (t) + Vt rows (dv)
    auto stageDiag = [&](int bufI) {
        #pragma unroll
        for (int l = 0; l < 2; ++l) {
            int off = l * 4096 + tid * 16;
            int row = off >> 7, cb = off & 127;
            int scb = swzb(row, cb);
            gload_lds16((const char*)kslab +
                            ((size_t)b * 1048576 + (size_t)(t0q + row) * E_DIM + colb) * 2 + scb,
                        (char*)&KB[bufI][0] + off);
            gload_lds16((const char*)vtb +
                            (((size_t)(b * 1024 + colb + row)) * 1024 + t0q) * 2 + scb,
                        (char*)&VB[bufI][0] + off);
        }
    };

    #pragma unroll
    for (int l = 0; l < 2; ++l) {                 // stage Q once
        int off = l * 4096 + tid * 16;
        int row = off >> 7, cb = off & 127;
        gload_lds16((const char*)qslab +
                        ((size_t)b * 1048576 + (size_t)(t0q + row) * E_DIM + colb) * 2
                        + swzb(row, cb),
                    (char*)Qs + off);
    }
    if (qt > 0) stageP(0, 0); else stageDiag(0);
    __syncthreads();

    f32x4 pacc[2][2] = {};                        // P[dk][dv] fp32
    int cur = 0;

    // P accumulation: 1 GEMM + 1 barrier per c-step
    for (int c = 0; c < qt; ++c) {
        if (c + 1 < qt) stageP(cur ^ 1, c + 1); else stageDiag(cur ^ 1);
        #pragma unroll
        for (int kk = 0; kk < 64; kk += 32) {
            bf16x8 af[2], bfr[2];
            #pragma unroll
            for (int ii = 0; ii < 2; ++ii) {
                int row = wr * 32 + ii * 16 + l15;     // dk
                af[ii] = *reinterpret_cast<const bf16x8*>(
                    &KB[cur][row * 64 + (swzb(row, (kk + l4 * 8) * 2) >> 1)]);
            }
            #pragma unroll
            for (int j = 0; j < 2; ++j) {
                int row = wc * 32 + j * 16 + l15;      // dv
                bfr[j] = *reinterpret_cast<const bf16x8*>(
                    &VB[cur][row * 64 + (swzb(row, (kk + l4 * 8) * 2) >> 1)]);
            }
            #pragma unroll
            for (int ii = 0; ii < 2; ++ii)
                #pragma unroll
                for (int j = 0; j < 2; ++j)
                    pacc[ii][j] = __builtin_amdgcn_mfma_f32_16x16x32_bf16(
                        af[ii], bfr[j], pacc[ii][j], 0, 0, 0);
        }
        __syncthreads();
        cur ^= 1;
    }

    // diag tiles now in buf[cur]: S = Q Kqt^T
    f32x4 sacc[2][2] = {};
    #pragma unroll
    for (int kk = 0; kk < 64; kk += 32) {
        bf16x8 af[2], bfr[2];
        #pragma unroll
        for (int ii = 0; ii < 2; ++ii) {
            int row = wr * 32 + ii * 16 + l15;         // t
            af[ii] = *reinterpret_cast<const bf16x8*>(
                &Qs[row * 64 + (swzb(row, (kk + l4 * 8) * 2) >> 1)]);
        }
        #pragma unroll
        for (int j = 0; j < 2; ++j) {
            int row = wc * 32 + j * 16 + l15;          // tk
            bfr[j] = *reinterpret_cast<const bf16x8*>(
                &KB[cur][row * 64 + (swzb(row, (kk + l4 * 8) * 2) >> 1)]);
        }
        #pragma unroll
        for (int ii = 0; ii < 2; ++ii)
            #pragma unroll
            for (int j = 0; j < 2; ++j)
                sacc[ii][j] = __builtin_amdgcn_mfma_f32_16x16x32_bf16(
                    af[ii], bfr[j], sacc[ii][j], 0, 0, 0);
    }

    // write P^T (bf16) and masked S to LDS
    #pragma unroll
    for (int ii = 0; ii < 2; ++ii) {
        #pragma unroll
        for (int j = 0; j < 2; ++j) {
            int dv = wc * 32 + j * 16 + l15;
            int dkb = wr * 32 + ii * 16 + l4 * 4;
            ushort4 pw;
            pw.x = f2bf(pacc[ii][j][0]); pw.y = f2bf(pacc[ii][j][1]);
            pw.z = f2bf(pacc[ii][j][2]); pw.w = f2bf(pacc[ii][j][3]);
            *reinterpret_cast<ushort4*>(&PTs[dv * 72 + dkb]) = pw;
            int kr = dv;                               // same lane mapping
            #pragma unroll
            for (int q = 0; q < 4; ++q) {
                int qr = dkb + q;                      // t row
                Ss[qr * 72 + kr] = (kr <= qr) ? (short)f2bf(sacc[ii][j][q]) : (short)0;
            }
        }
    }
    __syncthreads();

    // O = S @ Vqt + Q @ P
    f32x4 oacc[2][2] = {};
    #pragma unroll
    for (int kk = 0; kk < 64; kk += 32) {
        bf16x8 af[2], bfr[2];
        #pragma unroll
        for (int ii = 0; ii < 2; ++ii)
            af[ii] = *reinterpret_cast<const bf16x8*>(
                        &Ss[(wr * 32 + ii * 16 + l15) * 72 + kk + l4 * 8]);
        #pragma unroll
        for (int j = 0; j < 2; ++j) {
            int row = wc * 32 + j * 16 + l15;          // dv
            bfr[j] = *reinterpret_cast<const bf16x8*>(
                &VB[cur][row * 64 + (swzb(row, (kk + l4 * 8) * 2) >> 1)]);
        }
        #pragma unroll
        for (int ii = 0; ii < 2; ++ii)
            #pragma unroll
            for (int j = 0; j < 2; ++j)
                oacc[ii][j] = __builtin_amdgcn_mfma_f32_16x16x32_bf16(
                    af[ii], bfr[j], oacc[ii][j], 0, 0, 0);
    }
    #pragma unroll
    for (int kk = 0; kk < 64; kk += 32) {
        bf16x8 af[2], bfr[2];
        #pragma unroll
        for (int ii = 0; ii < 2; ++ii) {
            int row = wr * 32 + ii * 16 + l15;         // t
            af[ii] = *reinterpret_cast<const bf16x8*>(
                &Qs[row * 64 + (swzb(row, (kk + l4 * 8) * 2) >> 1)]);
        }
        #pragma unroll
        for (int j = 0; j < 2; ++j)
            bfr[j] = *reinterpret_cast<const bf16x8*>(
                        &PTs[(wc * 32 + j * 16 + l15) * 72 + kk + l4 * 8]);
        #pragma unroll
        for (int ii = 0; ii < 2; ++ii)
            #pragma unroll
            for (int j = 0; j < 2; ++j)
                oacc[ii][j] = __builtin_amdgcn_mfma_f32_16x16x32_bf16(
                    af[ii], bfr[j], oacc[ii][j], 0, 0, 0);
    }

    #pragma unroll
    for (int ii = 0; ii < 2; ++ii) {
        #pragma unroll
        for (int j = 0; j < 2; ++j) {
            int dv = wc * 32 + j * 16 + l15;
            #pragma unroll
            for (int q = 0; q < 4; ++q) {
                int qr = wr * 32 + ii * 16 + l4 * 4 + q;
                attnbf[(size_t)b * 1048576 + (size_t)(t0q + qr) * E_DIM + colb + dv] =
                    f2bf(oacc[ii][j][q] * 0.125f);
            }
        }
    }
}

// ---------------------------------------------------------------------------
// Kernel 3: out-projection GEMM, 64x64 tile, swizzled LDS, double-buffered.
// Grid 512 XCD-chunked. fp32 output rows r = t*2+b.
// ---------------------------------------------------------------------------
__global__ __launch_bounds__(256) void k_gout(
    const unsigned short* __restrict__ attnbf, const unsigned short* __restrict__ Wobf,
    const float* __restrict__ bias, float* __restrict__ out)
{
    const int i = blockIdx.x;
    const int tile = (i & 7) * 64 + (i >> 3);     // 512 = 8 * 64
    const int x = tile & 15, y = tile >> 4;
    const int nBase = x * 64;
    const int mBase = y * 64;                     // r-space (t*2+b)

    __shared__ short As[2][64 * 64];
    __shared__ short Bs[2][64 * 64];

    const int tid = threadIdx.x;
    const int lane = tid & 63, wave = tid >> 6;
    const int wr = wave >> 1, wc = wave & 1;
    const int l15 = lane & 15, l4 = lane >> 4;

    auto stage = [&](int bufI, int k0) {
        #pragma unroll
        for (int l = 0; l < 2; ++l) {
            int off = l * 4096 + tid * 16;
            int row = off >> 7, cb = off & 127;
            int scb = swzb(row, cb);
            gload_lds16((const char*)Wobf + ((size_t)(nBase + row) * E_DIM + k0) * 2 + scb,
                        (char*)&Bs[bufI][0] + off);
            int r = mBase + row, t = r >> 1, bb = r & 1;
            gload_lds16((const char*)attnbf +
                            ((size_t)bb * 1048576 + (size_t)t * E_DIM + k0) * 2 + scb,
                        (char*)&As[bufI][0] + off);
        }
    };

    f32x4 acc[2][2] = {};

    stage(0, 0);
    __syncthreads();
    int cur = 0;
    for (int it = 0; it < 16; ++it) {
        if (it < 15) stage(cur ^ 1, (it + 1) * 64);
        #pragma unroll
        for (int kk = 0; kk < 64; kk += 32) {
            bf16x8 af[2], bfr[2];
            #pragma unroll
            for (int ii = 0; ii < 2; ++ii) {
                int row = wr * 32 + ii * 16 + l15;
                af[ii] = *reinterpret_cast<const bf16x8*>(
                    &As[cur][row * 64 + (swzb(row, (kk + l4 * 8) * 2) >> 1)]);
            }
            #pragma unroll
            for (int j = 0; j < 2; ++j) {
                int row = wc * 32 + j * 16 + l15;
                bfr[j] = *reinterpret_cast<const bf16x8*>(
                    &Bs[cur][row * 64 + (swzb(row, (kk + l4 * 8) * 2) >> 1)]);
            }
            #pragma unroll
            for (int ii = 0; ii < 2; ++ii)
                #pragma unroll
                for (int j = 0; j < 2; ++j)
                    acc[ii][j] = __builtin_amdgcn_mfma_f32_16x16x32_bf16(
                        af[ii], bfr[j], acc[ii][j], 0, 0, 0);
        }
        __syncthreads();
        cur ^= 1;
    }

    #pragma unroll
    for (int ii = 0; ii < 2; ++ii) {
        int r0 = mBase + wr * 32 + ii * 16 + l4 * 4;
        #pragma unroll
        for (int j = 0; j < 2; ++j) {
            int col = nBase + wc * 32 + j * 16 + l15;
            float bv = bias[col];
            #pragma unroll
            for (int q = 0; q < 4; ++q)
                out[(size_t)(r0 + q) * E_DIM + col] = acc[ii][j][q] + bv;
        }
    }
}

// ---------------------------------------------------------------------------
extern "C" void kernel_launch(void* const* d_in, const int* in_sizes, int n_in,
                              void* d_out, int out_size, void* d_ws, size_t ws_size,
                              hipStream_t stream)
{
    const float* q_in  = (const float*)d_in[0];
    const float* k_in  = (const float*)d_in[1];
    const float* v_in  = (const float*)d_in[2];
    const float* w_in  = (const float*)d_in[3];
    const float* b_in  = (const float*)d_in[4];
    const float* w_out = (const float*)d_in[5];
    const float* b_out = (const float*)d_in[6];

    // ws layout (28 MiB):
    //   [ 0, 6M) Wibf bf16   [ 6M, 8M) Wobf bf16
    //   [ 8M,12M) qslab bf16 [b][t][e]   [12M,16M) kslab bf16 [b][t][e]
    //   [16M,20M) vtb bf16 [b][e][t]     [20M,24M) attnbf bf16 [b][t][e]
    //   [24M,28M) ktb bf16 [b][e][t]
    char* w = (char*)d_ws;
    unsigned short* Wibf   = (unsigned short*)w;
    unsigned short* Wobf   = (unsigned short*)(w + 6291456);
    unsigned short* qslab  = (unsigned short*)(w + 8388608);
    unsigned short* kslab  = (unsigned short*)(w + 12582912);
    unsigned short* vtb    = (unsigned short*)(w + 16777216);
    unsigned short* attnbf = (unsigned short*)(w + 20971520);
    unsigned short* ktb    = (unsigned short*)(w + 25165824);
    float* outp = (float*)d_out;

    k_castw<<<2048, 256, 0, stream>>>(w_in, w_out, Wibf);
    k_gin<<<384, 256, 0, stream>>>(q_in, k_in, v_in, Wibf, b_in,
                                   qslab, kslab, ktb, vtb);
    k_attn<<<512, 256, 0, stream>>>(qslab, kslab, ktb, vtb, attnbf);
    k_gout<<<512, 256, 0, stream>>>(attnbf, Wobf, b_out, outp);
}

// Round 9
// 145.950 us; speedup vs baseline: 1.0654x; 1.0131x over previous
//
#include <hip/hip_runtime.h>

// Round 9: (1) full pre-cast (X q/k/v + Wi + Wo -> bf16) so gin stages BOTH
// operands via global_load_lds (removes the exposed vmcnt stall of inline
// fp32 reg-cvt staging — T14 violation); (2) gin XCD chunking made x-inner:
// the 4 n-tiles of one (z,y) run consecutively on one XCD -> A-tile L2-hit
// 3/4, W z-slab (2MB) L2-resident per XCD. attn keeps round-8 prefix form.

#define E_DIM 1024

typedef short bf16x8 __attribute__((ext_vector_type(8)));
typedef float f32x4  __attribute__((ext_vector_type(4)));

__device__ inline unsigned short f2bf(float f) {
    unsigned u = __builtin_bit_cast(unsigned, f);
    u = (u + 0x7FFFu + ((u >> 16) & 1u)) >> 16;   // RNE; inputs finite
    return (unsigned short)u;
}

__device__ inline void gload_lds16(const void* g, void* l) {
    __builtin_amdgcn_global_load_lds(
        (const __attribute__((address_space(1))) unsigned int*)g,
        (__attribute__((address_space(3))) unsigned int*)l, 16, 0, 0);
}

// XOR swizzle within each 8-row stripe of a 128B-stride tile (involution).
__device__ inline int swzb(int row, int colbyte) {
    return colbyte ^ ((row & 7) << 4);
}

// ---------------------------------------------------------------------------
// Kernel 0: cast everything to bf16, contiguous dst:
//   [xq 2M][xk 2M][xv 2M][Wi 3M][Wo 1M] elements (10.5M total, 1310720 f8).
// ---------------------------------------------------------------------------
__global__ __launch_bounds__(256) void k_cast(
    const float* __restrict__ q_in, const float* __restrict__ k_in,
    const float* __restrict__ v_in, const float* __restrict__ w_in,
    const float* __restrict__ w_out, unsigned short* __restrict__ dst)
{
    #pragma unroll
    for (int l = 0; l < 4; ++l) {
        int id8 = blockIdx.x * 256 + threadIdx.x + l * 327680;
        const float* src;
        if (id8 < 262144)        src = q_in  + (size_t)id8 * 8;
        else if (id8 < 524288)   src = k_in  + (size_t)(id8 - 262144) * 8;
        else if (id8 < 786432)   src = v_in  + (size_t)(id8 - 524288) * 8;
        else if (id8 < 1179648)  src = w_in  + (size_t)(id8 - 786432) * 8;
        else                     src = w_out + (size_t)(id8 - 1179648) * 8;
        float4 f0 = *reinterpret_cast<const float4*>(src);
        float4 f1 = *reinterpret_cast<const float4*>(src + 4);
        ushort4 o0, o1;
        o0.x = f2bf(f0.x); o0.y = f2bf(f0.y); o0.z = f2bf(f0.z); o0.w = f2bf(f0.w);
        o1.x = f2bf(f1.x); o1.y = f2bf(f1.y); o1.z = f2bf(f1.z); o1.w = f2bf(f1.w);
        *reinterpret_cast<ushort4*>(dst + (size_t)id8 * 8)     = o0;
        *reinterpret_cast<ushort4*>(dst + (size_t)id8 * 8 + 4) = o1;
    }
}

// ---------------------------------------------------------------------------
// Kernel 1: in-projection GEMM, 64x256 tile, BK=64, double-buffered, one
// barrier/K-step, both operands bf16 via global_load_lds (swizzled source).
// Grid 384; block i -> xcd = i&7, slot j = i>>3; p = xcd*12 + (j>>2) selects
// (z,y), x = j&3 inner -> A-tile L2-hit across x, W z-slab L2-resident.
// Epilogue: z=0 Q natural; z=1 K natural + Kt; z=2 Vt only.
// ---------------------------------------------------------------------------
__global__ __launch_bounds__(256) void k_gin(
    const unsigned short* __restrict__ xbf, const unsigned short* __restrict__ Wibf,
    const float* __restrict__ b_in,
    unsigned short* __restrict__ qslab, unsigned short* __restrict__ kslab,
    unsigned short* __restrict__ ktb,   unsigned short* __restrict__ vtb)
{
    const int i = blockIdx.x;
    const int xcd = i & 7, j = i >> 3;            // j in 0..47
    const int p = xcd * 12 + (j >> 2);            // 0..95 -> (z,y)
    const int x = j & 3;
    const int z = p >> 5, y = p & 31;

    const unsigned short* X = xbf + (size_t)z * 2097152;
    const unsigned short* W = Wibf + (size_t)z * 1048576;
    const float* bz = b_in + z * E_DIM;

    const int nBase = x * 256;
    const int mBase = y * 64;                     // b-major row space
    const int b = mBase >> 10, tBase = mBase & 1023;

    __shared__ short As[2][64 * 64];              // 2 x 8 KB
    __shared__ short Bs[2][256 * 64];             // 2 x 32 KB

    const int tid = threadIdx.x;
    const int lane = tid & 63, wave = tid >> 6;
    const int wr = wave >> 1, wc = wave & 1;
    const int l15 = lane & 15, l4 = lane >> 4;

    auto stage = [&](int bufI, int k0) {
        #pragma unroll
        for (int l = 0; l < 8; ++l) {             // B: 256x64 bf16
            int off = l * 4096 + tid * 16;
            int row = off >> 7, cb = off & 127;
            gload_lds16((const char*)W + ((size_t)(nBase + row) * E_DIM + k0) * 2
                            + swzb(row, cb),
                        (char*)&Bs[bufI][0] + off);
        }
        #pragma unroll
        for (int l = 0; l < 2; ++l) {             // A: 64x64 bf16
            int off = l * 4096 + tid * 16;
            int row = off >> 7, cb = off & 127;
            gload_lds16((const char*)X +
                            ((size_t)((tBase + row) * 2 + b) * E_DIM + k0) * 2
                            + swzb(row, cb),
                        (char*)&As[bufI][0] + off);
        }
    };

    f32x4 acc[2][8] = {};

    stage(0, 0);
    __syncthreads();
    int cur = 0;
    for (int it = 0; it < 16; ++it) {
        if (it < 15) stage(cur ^ 1, (it + 1) * 64);
        #pragma unroll
        for (int kk = 0; kk < 64; kk += 32) {
            bf16x8 af[2], bfr[8];
            #pragma unroll
            for (int ii = 0; ii < 2; ++ii) {
                int row = wr * 32 + ii * 16 + l15;
                af[ii] = *reinterpret_cast<const bf16x8*>(
                    &As[cur][row * 64 + (swzb(row, (kk + l4 * 8) * 2) >> 1)]);
            }
            #pragma unroll
            for (int jn = 0; jn < 8; ++jn) {
                int row = wc * 128 + jn * 16 + l15;
                bfr[jn] = *reinterpret_cast<const bf16x8*>(
                    &Bs[cur][row * 64 + (swzb(row, (kk + l4 * 8) * 2) >> 1)]);
            }
            #pragma unroll
            for (int ii = 0; ii < 2; ++ii)
                #pragma unroll
                for (int jn = 0; jn < 8; ++jn)
                    acc[ii][jn] = __builtin_amdgcn_mfma_f32_16x16x32_bf16(
                        af[ii], bfr[jn], acc[ii][jn], 0, 0, 0);
        }
        __syncthreads();
        cur ^= 1;
    }

    #pragma unroll
    for (int ii = 0; ii < 2; ++ii) {
        int t0 = tBase + wr * 32 + ii * 16 + l4 * 4;
        #pragma unroll
        for (int jn = 0; jn < 8; ++jn) {
            int col = nBase + wc * 128 + jn * 16 + l15;
            float bv = bz[col];
            unsigned short v4[4];
            #pragma unroll
            for (int q = 0; q < 4; ++q) v4[q] = f2bf(acc[ii][jn][q] + bv);
            if (z == 0) {
                #pragma unroll
                for (int q = 0; q < 4; ++q)
                    qslab[(size_t)b * 1048576 + (size_t)(t0 + q) * E_DIM + col] = v4[q];
            } else if (z == 1) {
                #pragma unroll
                for (int q = 0; q < 4; ++q)
                    kslab[(size_t)b * 1048576 + (size_t)(t0 + q) * E_DIM + col] = v4[q];
                ushort4 w = {v4[0], v4[1], v4[2], v4[3]};
                *reinterpret_cast<ushort4*>(
                    &ktb[((size_t)b * 1024 + col) * 1024 + t0]) = w;
            } else {
                ushort4 w = {v4[0], v4[1], v4[2], v4[3]};
                *reinterpret_cast<ushort4*>(
                    &vtb[((size_t)b * 1024 + col) * 1024 + t0]) = w;
            }
        }
    }
}

// ---------------------------------------------------------------------------
// Kernel 2: chunked-prefix linear attention (round-8 form).
// Per block (bh, qt):
//   P[dk][dv] = sum_{c<qt} Kt_c . Vt_c   (fp32 acc, 1 GEMM + 1 barrier / c)
//   O = Q @ P  +  tril(Q Kqt^T) @ Vqt ;  attn = 0.125 * O  (bf16)
// Grid 512, XCD-chunked (4 bh/XCD); complementary qt pairing.
// ---------------------------------------------------------------------------
__global__ __launch_bounds__(256) void k_attn(
    const unsigned short* __restrict__ qslab, const unsigned short* __restrict__ kslab,
    const unsigned short* __restrict__ ktb,  const unsigned short* __restrict__ vtb,
    unsigned short* __restrict__ attnbf)
{
    const int i = blockIdx.x;
    const int xcd = i & 7, u = i >> 3;            // u in 0..63
    const int bh = xcd * 4 + (u >> 4);
    const int qtr = u & 15;
    const int qt = ((u >> 5) & 1) ? (15 - qtr) : qtr;
    const int b = bh >> 4, h = bh & 15;
    const int colb = h * 64, t0q = qt * 64;

    __shared__ short Qs[64 * 64];
    __shared__ short KB[2][64 * 64];              // Kt tiles / diag K natural
    __shared__ short VB[2][64 * 64];              // Vt tiles
    __shared__ short Ss[64 * 72];                 // masked S (padded)
    __shared__ short PTs[64 * 72];                // P^T bf16 (padded)

    const int tid = threadIdx.x;
    const int lane = tid & 63, wave = tid >> 6;
    const int wr = wave >> 1, wc = wave & 1;
    const int l15 = lane & 15, l4 = lane >> 4;

    auto stageP = [&](int bufI, int c) {
        int t0k = c * 64;
        #pragma unroll
        for (int l = 0; l < 2; ++l) {
            int off = l * 4096 + tid * 16;
            int row = off >> 7, cb = off & 127;
            int scb = swzb(row, cb);
            size_t trn = ((size_t)(b * 1024 + colb + row)) * 1024 + t0k;
            gload_lds16((const char*)ktb + trn * 2 + scb, (char*)&KB[bufI][0] + off);
            gload_lds16((const char*)vtb + trn * 2 + scb, (char*)&VB[bufI][0] + off);
        }
    };
    auto stageDiag = [&](int bufI) {
        #pragma unroll
        for (int l = 0; l < 2; ++l) {
            int off = l * 4096 + tid * 16;
            int row = off >> 7, cb = off & 127;
            int scb = swzb(row, cb);
            gload_lds16((const char*)kslab +
                            ((size_t)b * 1048576 + (size_t)(t0q + row) * E_DIM + colb) * 2 + scb,
                        (char*)&KB[bufI][0] + off);
            gload_lds16((const char*)vtb +
                            (((size_t)(b * 1024 + colb + row)) * 1024 + t0q) * 2 + scb,
                        (char*)&VB[bufI][0] + off);
        }
    };

    #pragma unroll
    for (int l = 0; l < 2; ++l) {                 // stage Q once
        int off = l * 4096 + tid * 16;
        int row = off >> 7, cb = off & 127;
        gload_lds16((const char*)qslab +
                        ((size_t)b * 1048576 + (size_t)(t0q + row) * E_DIM + colb) * 2
                        + swzb(row, cb),
                    (char*)Qs + off);
    }
    if (qt > 0) stageP(0, 0); else stageDiag(0);
    __syncthreads();

    f32x4 pacc[2][2] = {};                        // P[dk][dv] fp32
    int cur = 0;

    for (int c = 0; c < qt; ++c) {
        if (c + 1 < qt) stageP(cur ^ 1, c + 1); else stageDiag(cur ^ 1);
        #pragma unroll
        for (int kk = 0; kk < 64; kk += 32) {
            bf16x8 af[2], bfr[2];
            #pragma unroll
            for (int ii = 0; ii < 2; ++ii) {
                int row = wr * 32 + ii * 16 + l15;     // dk
                af[ii] = *reinterpret_cast<const bf16x8*>(
                    &KB[cur][row * 64 + (swzb(row, (kk + l4 * 8) * 2) >> 1)]);
            }
            #pragma unroll
            for (int jn = 0; jn < 2; ++jn) {
                int row = wc * 32 + jn * 16 + l15;     // dv
                bfr[jn] = *reinterpret_cast<const bf16x8*>(
                    &VB[cur][row * 64 + (swzb(row, (kk + l4 * 8) * 2) >> 1)]);
            }
            #pragma unroll
            for (int ii = 0; ii < 2; ++ii)
                #pragma unroll
                for (int jn = 0; jn < 2; ++jn)
                    pacc[ii][jn] = __builtin_amdgcn_mfma_f32_16x16x32_bf16(
                        af[ii], bfr[jn], pacc[ii][jn], 0, 0, 0);
        }
        __syncthreads();
        cur ^= 1;
    }

    // diag tiles in buf[cur]: S = Q Kqt^T
    f32x4 sacc[2][2] = {};
    #pragma unroll
    for (int kk = 0; kk < 64; kk += 32) {
        bf16x8 af[2], bfr[2];
        #pragma unroll
        for (int ii = 0; ii < 2; ++ii) {
            int row = wr * 32 + ii * 16 + l15;         // t
            af[ii] = *reinterpret_cast<const bf16x8*>(
                &Qs[row * 64 + (swzb(row, (kk + l4 * 8) * 2) >> 1)]);
        }
        #pragma unroll
        for (int jn = 0; jn < 2; ++jn) {
            int row = wc * 32 + jn * 16 + l15;         // tk
            bfr[jn] = *reinterpret_cast<const bf16x8*>(
                &KB[cur][row * 64 + (swzb(row, (kk + l4 * 8) * 2) >> 1)]);
        }
        #pragma unroll
        for (int ii = 0; ii < 2; ++ii)
            #pragma unroll
            for (int jn = 0; jn < 2; ++jn)
                sacc[ii][jn] = __builtin_amdgcn_mfma_f32_16x16x32_bf16(
                    af[ii], bfr[jn], sacc[ii][jn], 0, 0, 0);
    }

    // write P^T (bf16) and masked S to LDS
    #pragma unroll
    for (int ii = 0; ii < 2; ++ii) {
        #pragma unroll
        for (int jn = 0; jn < 2; ++jn) {
            int dv = wc * 32 + jn * 16 + l15;
            int dkb = wr * 32 + ii * 16 + l4 * 4;
            ushort4 pw;
            pw.x = f2bf(pacc[ii][jn][0]); pw.y = f2bf(pacc[ii][jn][1]);
            pw.z = f2bf(pacc[ii][jn][2]); pw.w = f2bf(pacc[ii][jn][3]);
            *reinterpret_cast<ushort4*>(&PTs[dv * 72 + dkb]) = pw;
            int kr = dv;
            #pragma unroll
            for (int q = 0; q < 4; ++q) {
                int qr = dkb + q;
                Ss[qr * 72 + kr] = (kr <= qr) ? (short)f2bf(sacc[ii][jn][q]) : (short)0;
            }
        }
    }
    __syncthreads();

    // O = S @ Vqt + Q @ P
    f32x4 oacc[2][2] = {};
    #pragma unroll
    for (int kk = 0; kk < 64; kk += 32) {
        bf16x8 af[2], bfr[2];
        #pragma unroll
        for (int ii = 0; ii < 2; ++ii)
            af[ii] = *reinterpret_cast<const bf16x8*>(
                        &Ss[(wr * 32 + ii * 16 + l15) * 72 + kk + l4 * 8]);
        #pragma unroll
        for (int jn = 0; jn < 2; ++jn) {
            int row = wc * 32 + jn * 16 + l15;         // dv
            bfr[jn] = *reinterpret_cast<const bf16x8*>(
                &VB[cur][row * 64 + (swzb(row, (kk + l4 * 8) * 2) >> 1)]);
        }
        #pragma unroll
        for (int ii = 0; ii < 2; ++ii)
            #pragma unroll
            for (int jn = 0; jn < 2; ++jn)
                oacc[ii][jn] = __builtin_amdgcn_mfma_f32_16x16x32_bf16(
                    af[ii], bfr[jn], oacc[ii][jn], 0, 0, 0);
    }
    #pragma unroll
    for (int kk = 0; kk < 64; kk += 32) {
        bf16x8 af[2], bfr[2];
        #pragma unroll
        for (int ii = 0; ii < 2; ++ii) {
            int row = wr * 32 + ii * 16 + l15;         // t
            af[ii] = *reinterpret_cast<const bf16x8*>(
                &Qs[row * 64 + (swzb(row, (kk + l4 * 8) * 2) >> 1)]);
        }
        #pragma unroll
        for (int jn = 0; jn < 2; ++jn)
            bfr[jn] = *reinterpret_cast<const bf16x8*>(
                        &PTs[(wc * 32 + jn * 16 + l15) * 72 + kk + l4 * 8]);
        #pragma unroll
        for (int ii = 0; ii < 2; ++ii)
            #pragma unroll
            for (int jn = 0; jn < 2; ++jn)
                oacc[ii][jn] = __builtin_amdgcn_mfma_f32_16x16x32_bf16(
                    af[ii], bfr[jn], oacc[ii][jn], 0, 0, 0);
    }

    #pragma unroll
    for (int ii = 0; ii < 2; ++ii) {
        #pragma unroll
        for (int jn = 0; jn < 2; ++jn) {
            int dv = wc * 32 + jn * 16 + l15;
            #pragma unroll
            for (int q = 0; q < 4; ++q) {
                int qr = wr * 32 + ii * 16 + l4 * 4 + q;
                attnbf[(size_t)b * 1048576 + (size_t)(t0q + qr) * E_DIM + colb + dv] =
                    f2bf(oacc[ii][jn][q] * 0.125f);
            }
        }
    }
}

// ---------------------------------------------------------------------------
// Kernel 3: out-projection GEMM, 64x64 tile, swizzled LDS, double-buffered.
// Grid 512 XCD-chunked. fp32 output rows r = t*2+b.
// ---------------------------------------------------------------------------
__global__ __launch_bounds__(256) void k_gout(
    const unsigned short* __restrict__ attnbf, const unsigned short* __restrict__ Wobf,
    const float* __restrict__ bias, float* __restrict__ out)
{
    const int i = blockIdx.x;
    const int tile = (i & 7) * 64 + (i >> 3);     // 512 = 8 * 64
    const int x = tile & 15, y = tile >> 4;
    const int nBase = x * 64;
    const int mBase = y * 64;                     // r-space (t*2+b)

    __shared__ short As[2][64 * 64];
    __shared__ short Bs[2][64 * 64];

    const int tid = threadIdx.x;
    const int lane = tid & 63, wave = tid >> 6;
    const int wr = wave >> 1, wc = wave & 1;
    const int l15 = lane & 15, l4 = lane >> 4;

    auto stage = [&](int bufI, int k0) {
        #pragma unroll
        for (int l = 0; l < 2; ++l) {
            int off = l * 4096 + tid * 16;
            int row = off >> 7, cb = off & 127;
            int scb = swzb(row, cb);
            gload_lds16((const char*)Wobf + ((size_t)(nBase + row) * E_DIM + k0) * 2 + scb,
                        (char*)&Bs[bufI][0] + off);
            int r = mBase + row, t = r >> 1, bb = r & 1;
            gload_lds16((const char*)attnbf +
                            ((size_t)bb * 1048576 + (size_t)t * E_DIM + k0) * 2 + scb,
                        (char*)&As[bufI][0] + off);
        }
    };

    f32x4 acc[2][2] = {};

    stage(0, 0);
    __syncthreads();
    int cur = 0;
    for (int it = 0; it < 16; ++it) {
        if (it < 15) stage(cur ^ 1, (it + 1) * 64);
        #pragma unroll
        for (int kk = 0; kk < 64; kk += 32) {
            bf16x8 af[2], bfr[2];
            #pragma unroll
            for (int ii = 0; ii < 2; ++ii) {
                int row = wr * 32 + ii * 16 + l15;
                af[ii] = *reinterpret_cast<const bf16x8*>(
                    &As[cur][row * 64 + (swzb(row, (kk + l4 * 8) * 2) >> 1)]);
            }
            #pragma unroll
            for (int jn = 0; jn < 2; ++jn) {
                int row = wc * 32 + jn * 16 + l15;
                bfr[jn] = *reinterpret_cast<const bf16x8*>(
                    &Bs[cur][row * 64 + (swzb(row, (kk + l4 * 8) * 2) >> 1)]);
            }
            #pragma unroll
            for (int ii = 0; ii < 2; ++ii)
                #pragma unroll
                for (int jn = 0; jn < 2; ++jn)
                    acc[ii][jn] = __builtin_amdgcn_mfma_f32_16x16x32_bf16(
                        af[ii], bfr[jn], acc[ii][jn], 0, 0, 0);
        }
        __syncthreads();
        cur ^= 1;
    }

    #pragma unroll
    for (int ii = 0; ii < 2; ++ii) {
        int r0 = mBase + wr * 32 + ii * 16 + l4 * 4;
        #pragma unroll
        for (int jn = 0; jn < 2; ++jn) {
            int col = nBase + wc * 32 + jn * 16 + l15;
            float bv = bias[col];
            #pragma unroll
            for (int q = 0; q < 4; ++q)
                out[(size_t)(r0 + q) * E_DIM + col] = acc[ii][jn][q] + bv;
        }
    }
}

// ---------------------------------------------------------------------------
extern "C" void kernel_launch(void* const* d_in, const int* in_sizes, int n_in,
                              void* d_out, int out_size, void* d_ws, size_t ws_size,
                              hipStream_t stream)
{
    const float* q_in  = (const float*)d_in[0];
    const float* k_in  = (const float*)d_in[1];
    const float* v_in  = (const float*)d_in[2];
    const float* w_in  = (const float*)d_in[3];
    const float* b_in  = (const float*)d_in[4];
    const float* w_out = (const float*)d_in[5];
    const float* b_out = (const float*)d_in[6];

    // ws layout (40 MiB):
    //   [ 0,12M) xbf bf16 [xq|xk|xv]     [12M,18M) Wibf bf16
    //   [18M,20M) Wobf bf16
    //   [20M,24M) qslab bf16 [b][t][e]   [24M,28M) kslab bf16 [b][t][e]
    //   [28M,32M) ktb bf16 [b][e][t]     [32M,36M) vtb bf16 [b][e][t]
    //   [36M,40M) attnbf bf16 [b][t][e]
    char* w = (char*)d_ws;
    unsigned short* xbf    = (unsigned short*)w;
    unsigned short* Wibf   = (unsigned short*)(w + 12582912);
    unsigned short* Wobf   = (unsigned short*)(w + 18874368);
    unsigned short* qslab  = (unsigned short*)(w + 20971520);
    unsigned short* kslab  = (unsigned short*)(w + 25165824);
    unsigned short* ktb    = (unsigned short*)(w + 29360128);
    unsigned short* vtb    = (unsigned short*)(w + 33554432);
    unsigned short* attnbf = (unsigned short*)(w + 37748736);
    float* outp = (float*)d_out;

    k_cast<<<1280, 256, 0, stream>>>(q_in, k_in, v_in, w_in, w_out, xbf);
    k_gin<<<384, 256, 0, stream>>>(xbf, Wibf, b_in, qslab, kslab, ktb, vtb);
    k_attn<<<512, 256, 0, stream>>>(qslab, kslab, ktb, vtb, attnbf);
    k_gout<<<512, 256, 0, stream>>>(attnbf, Wobf, b_out, outp);
}

// Round 11
// 141.866 us; speedup vs baseline: 1.0960x; 1.0288x over previous
//
#include <hip/hip_runtime.h>

// Round 11: resubmission of Round-10 kernel (bench was GPUAcquisitionTimeout —
// no signal). T4 counted-vmcnt 2-deep pipelines (prologue stages tiles 0,1;
// loop: s_waitcnt vmcnt(N_in_flight) -> s_barrier -> MFMA(cur) -> s_barrier
// -> stage(tile+2)) in gin / attn P-loop / gout. No vmcnt(0) drain in any
// main loop. Everything else identical to round 9.

#define E_DIM 1024

typedef short bf16x8 __attribute__((ext_vector_type(8)));
typedef float f32x4  __attribute__((ext_vector_type(4)));

__device__ inline unsigned short f2bf(float f) {
    unsigned u = __builtin_bit_cast(unsigned, f);
    u = (u + 0x7FFFu + ((u >> 16) & 1u)) >> 16;   // RNE; inputs finite
    return (unsigned short)u;
}

__device__ inline void gload_lds16(const void* g, void* l) {
    __builtin_amdgcn_global_load_lds(
        (const __attribute__((address_space(1))) unsigned int*)g,
        (__attribute__((address_space(3))) unsigned int*)l, 16, 0, 0);
}

// XOR swizzle within each 8-row stripe of a 128B-stride tile (involution).
__device__ inline int swzb(int row, int colbyte) {
    return colbyte ^ ((row & 7) << 4);
}

#define WAIT_VM(N) do { \
    asm volatile("s_waitcnt vmcnt(" #N ")" ::: "memory"); \
    __builtin_amdgcn_sched_barrier(0); } while (0)

// ---------------------------------------------------------------------------
// Kernel 0: cast everything to bf16, contiguous dst:
//   [xq 2M][xk 2M][xv 2M][Wi 3M][Wo 1M] elements.
// ---------------------------------------------------------------------------
__global__ __launch_bounds__(256) void k_cast(
    const float* __restrict__ q_in, const float* __restrict__ k_in,
    const float* __restrict__ v_in, const float* __restrict__ w_in,
    const float* __restrict__ w_out, unsigned short* __restrict__ dst)
{
    #pragma unroll
    for (int l = 0; l < 4; ++l) {
        int id8 = blockIdx.x * 256 + threadIdx.x + l * 327680;
        const float* src;
        if (id8 < 262144)        src = q_in  + (size_t)id8 * 8;
        else if (id8 < 524288)   src = k_in  + (size_t)(id8 - 262144) * 8;
        else if (id8 < 786432)   src = v_in  + (size_t)(id8 - 524288) * 8;
        else if (id8 < 1179648)  src = w_in  + (size_t)(id8 - 786432) * 8;
        else                     src = w_out + (size_t)(id8 - 1179648) * 8;
        float4 f0 = *reinterpret_cast<const float4*>(src);
        float4 f1 = *reinterpret_cast<const float4*>(src + 4);
        ushort4 o0, o1;
        o0.x = f2bf(f0.x); o0.y = f2bf(f0.y); o0.z = f2bf(f0.z); o0.w = f2bf(f0.w);
        o1.x = f2bf(f1.x); o1.y = f2bf(f1.y); o1.z = f2bf(f1.z); o1.w = f2bf(f1.w);
        *reinterpret_cast<ushort4*>(dst + (size_t)id8 * 8)     = o0;
        *reinterpret_cast<ushort4*>(dst + (size_t)id8 * 8 + 4) = o1;
    }
}

// ---------------------------------------------------------------------------
// Kernel 1: in-projection GEMM, 64x256 tile, BK=64, counted-vmcnt 2-deep.
// Stage = 10 gload_lds/thread (B 8 + A 2). Grid 384, XCD x-inner chunking.
// Epilogue: z=0 Q natural; z=1 K natural + Kt; z=2 Vt only.
// ---------------------------------------------------------------------------
__global__ __launch_bounds__(256) void k_gin(
    const unsigned short* __restrict__ xbf, const unsigned short* __restrict__ Wibf,
    const float* __restrict__ b_in,
    unsigned short* __restrict__ qslab, unsigned short* __restrict__ kslab,
    unsigned short* __restrict__ ktb,   unsigned short* __restrict__ vtb)
{
    const int i = blockIdx.x;
    const int xcd = i & 7, j = i >> 3;            // j in 0..47
    const int p = xcd * 12 + (j >> 2);            // 0..95 -> (z,y)
    const int x = j & 3;
    const int z = p >> 5, y = p & 31;

    const unsigned short* X = xbf + (size_t)z * 2097152;
    const unsigned short* W = Wibf + (size_t)z * 1048576;
    const float* bz = b_in + z * E_DIM;

    const int nBase = x * 256;
    const int mBase = y * 64;                     // b-major row space
    const int b = mBase >> 10, tBase = mBase & 1023;

    __shared__ short As[2][64 * 64];              // 2 x 8 KB
    __shared__ short Bs[2][256 * 64];             // 2 x 32 KB

    const int tid = threadIdx.x;
    const int lane = tid & 63, wave = tid >> 6;
    const int wr = wave >> 1, wc = wave & 1;
    const int l15 = lane & 15, l4 = lane >> 4;

    auto stage = [&](int bufI, int it) {
        int k0 = it * 64;
        #pragma unroll
        for (int l = 0; l < 8; ++l) {             // B: 256x64 bf16
            int off = l * 4096 + tid * 16;
            int row = off >> 7, cb = off & 127;
            gload_lds16((const char*)W + ((size_t)(nBase + row) * E_DIM + k0) * 2
                            + swzb(row, cb),
                        (char*)&Bs[bufI][0] + off);
        }
        #pragma unroll
        for (int l = 0; l < 2; ++l) {             // A: 64x64 bf16
            int off = l * 4096 + tid * 16;
            int row = off >> 7, cb = off & 127;
            gload_lds16((const char*)X +
                            ((size_t)((tBase + row) * 2 + b) * E_DIM + k0) * 2
                            + swzb(row, cb),
                        (char*)&As[bufI][0] + off);
        }
    };

    f32x4 acc[2][8] = {};

    stage(0, 0);
    stage(1, 1);
    for (int it = 0; it < 16; ++it) {
        if (it < 15) WAIT_VM(10); else WAIT_VM(0);   // cur tile landed (mine)
        __builtin_amdgcn_s_barrier();                // ...and everyone's
        const int cur = it & 1;
        #pragma unroll
        for (int kk = 0; kk < 64; kk += 32) {
            bf16x8 af[2], bfr[8];
            #pragma unroll
            for (int ii = 0; ii < 2; ++ii) {
                int row = wr * 32 + ii * 16 + l15;
                af[ii] = *reinterpret_cast<const bf16x8*>(
                    &As[cur][row * 64 + (swzb(row, (kk + l4 * 8) * 2) >> 1)]);
            }
            #pragma unroll
            for (int jn = 0; jn < 8; ++jn) {
                int row = wc * 128 + jn * 16 + l15;
                bfr[jn] = *reinterpret_cast<const bf16x8*>(
                    &Bs[cur][row * 64 + (swzb(row, (kk + l4 * 8) * 2) >> 1)]);
            }
            #pragma unroll
            for (int ii = 0; ii < 2; ++ii)
                #pragma unroll
                for (int jn = 0; jn < 8; ++jn)
                    acc[ii][jn] = __builtin_amdgcn_mfma_f32_16x16x32_bf16(
                        af[ii], bfr[jn], acc[ii][jn], 0, 0, 0);
        }
        __builtin_amdgcn_s_barrier();                // all reads of cur done
        __builtin_amdgcn_sched_barrier(0);
        if (it + 2 < 16) stage(cur, it + 2);         // refill freed buffer
    }

    #pragma unroll
    for (int ii = 0; ii < 2; ++ii) {
        int t0 = tBase + wr * 32 + ii * 16 + l4 * 4;
        #pragma unroll
        for (int jn = 0; jn < 8; ++jn) {
            int col = nBase + wc * 128 + jn * 16 + l15;
            float bv = bz[col];
            unsigned short v4[4];
            #pragma unroll
            for (int q = 0; q < 4; ++q) v4[q] = f2bf(acc[ii][jn][q] + bv);
            if (z == 0) {
                #pragma unroll
                for (int q = 0; q < 4; ++q)
                    qslab[(size_t)b * 1048576 + (size_t)(t0 + q) * E_DIM + col] = v4[q];
            } else if (z == 1) {
                #pragma unroll
                for (int q = 0; q < 4; ++q)
                    kslab[(size_t)b * 1048576 + (size_t)(t0 + q) * E_DIM + col] = v4[q];
                ushort4 w = {v4[0], v4[1], v4[2], v4[3]};
                *reinterpret_cast<ushort4*>(
                    &ktb[((size_t)b * 1024 + col) * 1024 + t0]) = w;
            } else {
                ushort4 w = {v4[0], v4[1], v4[2], v4[3]};
                *reinterpret_cast<ushort4*>(
                    &vtb[((size_t)b * 1024 + col) * 1024 + t0]) = w;
            }
        }
    }
}

// ---------------------------------------------------------------------------
// Kernel 2: chunked-prefix linear attention, counted-vmcnt 2-deep P-loop.
// Tiles tau = 0..qt: tau<qt -> P chunk (Kt,Vt); tau==qt -> diag (K nat, Vt).
// Stage = 4 gload_lds/thread. Grid 512, XCD-chunked, complementary pairing.
// ---------------------------------------------------------------------------
__global__ __launch_bounds__(256) void k_attn(
    const unsigned short* __restrict__ qslab, const unsigned short* __restrict__ kslab,
    const unsigned short* __restrict__ ktb,  const unsigned short* __restrict__ vtb,
    unsigned short* __restrict__ attnbf)
{
    const int i = blockIdx.x;
    const int xcd = i & 7, u = i >> 3;            // u in 0..63
    const int bh = xcd * 4 + (u >> 4);
    const int qtr = u & 15;
    const int qt = ((u >> 5) & 1) ? (15 - qtr) : qtr;
    const int b = bh >> 4, h = bh & 15;
    const int colb = h * 64, t0q = qt * 64;

    __shared__ short Qs[64 * 64];
    __shared__ short KB[2][64 * 64];              // Kt tiles / diag K natural
    __shared__ short VB[2][64 * 64];              // Vt tiles
    __shared__ short Ss[64 * 72];                 // masked S (padded)
    __shared__ short PTs[64 * 72];                // P^T bf16 (padded)

    const int tid = threadIdx.x;
    const int lane = tid & 63, wave = tid >> 6;
    const int wr = wave >> 1, wc = wave & 1;
    const int l15 = lane & 15, l4 = lane >> 4;

    // unified tile stage: tau < qt -> P chunk; tau == qt -> diag
    auto stage = [&](int bufI, int tau) {
        #pragma unroll
        for (int l = 0; l < 2; ++l) {
            int off = l * 4096 + tid * 16;
            int row = off >> 7, cb = off & 127;
            int scb = swzb(row, cb);
            if (tau < qt) {
                size_t trn = ((size_t)(b * 1024 + colb + row)) * 1024 + tau * 64;
                gload_lds16((const char*)ktb + trn * 2 + scb, (char*)&KB[bufI][0] + off);
                gload_lds16((const char*)vtb + trn * 2 + scb, (char*)&VB[bufI][0] + off);
            } else {
                gload_lds16((const char*)kslab +
                                ((size_t)b * 1048576 + (size_t)(t0q + row) * E_DIM + colb) * 2 + scb,
                            (char*)&KB[bufI][0] + off);
                gload_lds16((const char*)vtb +
                                (((size_t)(b * 1024 + colb + row)) * 1024 + t0q) * 2 + scb,
                            (char*)&VB[bufI][0] + off);
            }
        }
    };

    #pragma unroll
    for (int l = 0; l < 2; ++l) {                 // stage Q once (2 ops)
        int off = l * 4096 + tid * 16;
        int row = off >> 7, cb = off & 127;
        gload_lds16((const char*)qslab +
                        ((size_t)b * 1048576 + (size_t)(t0q + row) * E_DIM + colb) * 2
                        + swzb(row, cb),
                    (char*)Qs + off);
    }
    stage(0, 0);
    if (qt >= 1) stage(1, 1);

    f32x4 pacc[2][2] = {};                        // P[dk][dv] fp32

    // P accumulation over tau = 0..qt-1 (counted vmcnt: next tile always in flight)
    for (int tau = 0; tau < qt; ++tau) {
        WAIT_VM(4);                               // tile tau landed (mine)
        __builtin_amdgcn_s_barrier();
        const int cur = tau & 1;
        #pragma unroll
        for (int kk = 0; kk < 64; kk += 32) {
            bf16x8 af[2], bfr[2];
            #pragma unroll
            for (int ii = 0; ii < 2; ++ii) {
                int row = wr * 32 + ii * 16 + l15;     // dk
                af[ii] = *reinterpret_cast<const bf16x8*>(
                    &KB[cur][row * 64 + (swzb(row, (kk + l4 * 8) * 2) >> 1)]);
            }
            #pragma unroll
            for (int jn = 0; jn < 2; ++jn) {
                int row = wc * 32 + jn * 16 + l15;     // dv
                bfr[jn] = *reinterpret_cast<const bf16x8*>(
                    &VB[cur][row * 64 + (swzb(row, (kk + l4 * 8) * 2) >> 1)]);
            }
            #pragma unroll
            for (int ii = 0; ii < 2; ++ii)
                #pragma unroll
                for (int jn = 0; jn < 2; ++jn)
                    pacc[ii][jn] = __builtin_amdgcn_mfma_f32_16x16x32_bf16(
                        af[ii], bfr[jn], pacc[ii][jn], 0, 0, 0);
        }
        __builtin_amdgcn_s_barrier();
        __builtin_amdgcn_sched_barrier(0);
        if (tau + 2 <= qt) stage(cur, tau + 2);
    }

    // diag tile (tau = qt) in buf[qt&1]
    WAIT_VM(0);
    __builtin_amdgcn_s_barrier();
    const int dcur = qt & 1;

    f32x4 sacc[2][2] = {};
    #pragma unroll
    for (int kk = 0; kk < 64; kk += 32) {
        bf16x8 af[2], bfr[2];
        #pragma unroll
        for (int ii = 0; ii < 2; ++ii) {
            int row = wr * 32 + ii * 16 + l15;         // t
            af[ii] = *reinterpret_cast<const bf16x8*>(
                &Qs[row * 64 + (swzb(row, (kk + l4 * 8) * 2) >> 1)]);
        }
        #pragma unroll
        for (int jn = 0; jn < 2; ++jn) {
            int row = wc * 32 + jn * 16 + l15;         // tk
            bfr[jn] = *reinterpret_cast<const bf16x8*>(
                &KB[dcur][row * 64 + (swzb(row, (kk + l4 * 8) * 2) >> 1)]);
        }
        #pragma unroll
        for (int ii = 0; ii < 2; ++ii)
            #pragma unroll
            for (int jn = 0; jn < 2; ++jn)
                sacc[ii][jn] = __builtin_amdgcn_mfma_f32_16x16x32_bf16(
                    af[ii], bfr[jn], sacc[ii][jn], 0, 0, 0);
    }

    // write P^T (bf16) and masked S to LDS
    #pragma unroll
    for (int ii = 0; ii < 2; ++ii) {
        #pragma unroll
        for (int jn = 0; jn < 2; ++jn) {
            int dv = wc * 32 + jn * 16 + l15;
            int dkb = wr * 32 + ii * 16 + l4 * 4;
            ushort4 pw;
            pw.x = f2bf(pacc[ii][jn][0]); pw.y = f2bf(pacc[ii][jn][1]);
            pw.z = f2bf(pacc[ii][jn][2]); pw.w = f2bf(pacc[ii][jn][3]);
            *reinterpret_cast<ushort4*>(&PTs[dv * 72 + dkb]) = pw;
            int kr = dv;
            #pragma unroll
            for (int q = 0; q < 4; ++q) {
                int qr = dkb + q;
                Ss[qr * 72 + kr] = (kr <= qr) ? (short)f2bf(sacc[ii][jn][q]) : (short)0;
            }
        }
    }
    __syncthreads();

    // O = S @ Vqt + Q @ P
    f32x4 oacc[2][2] = {};
    #pragma unroll
    for (int kk = 0; kk < 64; kk += 32) {
        bf16x8 af[2], bfr[2];
        #pragma unroll
        for (int ii = 0; ii < 2; ++ii)
            af[ii] = *reinterpret_cast<const bf16x8*>(
                        &Ss[(wr * 32 + ii * 16 + l15) * 72 + kk + l4 * 8]);
        #pragma unroll
        for (int jn = 0; jn < 2; ++jn) {
            int row = wc * 32 + jn * 16 + l15;         // dv
            bfr[jn] = *reinterpret_cast<const bf16x8*>(
                &VB[dcur][row * 64 + (swzb(row, (kk + l4 * 8) * 2) >> 1)]);
        }
        #pragma unroll
        for (int ii = 0; ii < 2; ++ii)
            #pragma unroll
            for (int jn = 0; jn < 2; ++jn)
                oacc[ii][jn] = __builtin_amdgcn_mfma_f32_16x16x32_bf16(
                    af[ii], bfr[jn], oacc[ii][jn], 0, 0, 0);
    }
    #pragma unroll
    for (int kk = 0; kk < 64; kk += 32) {
        bf16x8 af[2], bfr[2];
        #pragma unroll
        for (int ii = 0; ii < 2; ++ii) {
            int row = wr * 32 + ii * 16 + l15;         // t
            af[ii] = *reinterpret_cast<const bf16x8*>(
                &Qs[row * 64 + (swzb(row, (kk + l4 * 8) * 2) >> 1)]);
        }
        #pragma unroll
        for (int jn = 0; jn < 2; ++jn)
            bfr[jn] = *reinterpret_cast<const bf16x8*>(
                        &PTs[(wc * 32 + jn * 16 + l15) * 72 + kk + l4 * 8]);
        #pragma unroll
        for (int ii = 0; ii < 2; ++ii)
            #pragma unroll
            for (int jn = 0; jn < 2; ++jn)
                oacc[ii][jn] = __builtin_amdgcn_mfma_f32_16x16x32_bf16(
                    af[ii], bfr[jn], oacc[ii][jn], 0, 0, 0);
    }

    #pragma unroll
    for (int ii = 0; ii < 2; ++ii) {
        #pragma unroll
        for (int jn = 0; jn < 2; ++jn) {
            int dv = wc * 32 + jn * 16 + l15;
            #pragma unroll
            for (int q = 0; q < 4; ++q) {
                int qr = wr * 32 + ii * 16 + l4 * 4 + q;
                attnbf[(size_t)b * 1048576 + (size_t)(t0q + qr) * E_DIM + colb + dv] =
                    f2bf(oacc[ii][jn][q] * 0.125f);
            }
        }
    }
}

// ---------------------------------------------------------------------------
// Kernel 3: out-projection GEMM, 64x64 tile, counted-vmcnt 2-deep.
// Stage = 4 gload_lds/thread. Grid 512 XCD-chunked. fp32 out rows r = t*2+b.
// ---------------------------------------------------------------------------
__global__ __launch_bounds__(256) void k_gout(
    const unsigned short* __restrict__ attnbf, const unsigned short* __restrict__ Wobf,
    const float* __restrict__ bias, float* __restrict__ out)
{
    const int i = blockIdx.x;
    const int tile = (i & 7) * 64 + (i >> 3);     // 512 = 8 * 64
    const int x = tile & 15, y = tile >> 4;
    const int nBase = x * 64;
    const int mBase = y * 64;                     // r-space (t*2+b)

    __shared__ short As[2][64 * 64];
    __shared__ short Bs[2][64 * 64];

    const int tid = threadIdx.x;
    const int lane = tid & 63, wave = tid >> 6;
    const int wr = wave >> 1, wc = wave & 1;
    const int l15 = lane & 15, l4 = lane >> 4;

    auto stage = [&](int bufI, int it) {
        int k0 = it * 64;
        #pragma unroll
        for (int l = 0; l < 2; ++l) {
            int off = l * 4096 + tid * 16;
            int row = off >> 7, cb = off & 127;
            int scb = swzb(row, cb);
            gload_lds16((const char*)Wobf + ((size_t)(nBase + row) * E_DIM + k0) * 2 + scb,
                        (char*)&Bs[bufI][0] + off);
            int r = mBase + row, t = r >> 1, bb = r & 1;
            gload_lds16((const char*)attnbf +
                            ((size_t)bb * 1048576 + (size_t)t * E_DIM + k0) * 2 + scb,
                        (char*)&As[bufI][0] + off);
        }
    };

    f32x4 acc[2][2] = {};

    stage(0, 0);
    stage(1, 1);
    for (int it = 0; it < 16; ++it) {
        if (it < 15) WAIT_VM(4); else WAIT_VM(0);
        __builtin_amdgcn_s_barrier();
        const int cur = it & 1;
        #pragma unroll
        for (int kk = 0; kk < 64; kk += 32) {
            bf16x8 af[2], bfr[2];
            #pragma unroll
            for (int ii = 0; ii < 2; ++ii) {
                int row = wr * 32 + ii * 16 + l15;
                af[ii] = *reinterpret_cast<const bf16x8*>(
                    &As[cur][row * 64 + (swzb(row, (kk + l4 * 8) * 2) >> 1)]);
            }
            #pragma unroll
            for (int jn = 0; jn < 2; ++jn) {
                int row = wc * 32 + jn * 16 + l15;
                bfr[jn] = *reinterpret_cast<const bf16x8*>(
                    &Bs[cur][row * 64 + (swzb(row, (kk + l4 * 8) * 2) >> 1)]);
            }
            #pragma unroll
            for (int ii = 0; ii < 2; ++ii)
                #pragma unroll
                for (int jn = 0; jn < 2; ++jn)
                    acc[ii][jn] = __builtin_amdgcn_mfma_f32_16x16x32_bf16(
                        af[ii], bfr[jn], acc[ii][jn], 0, 0, 0);
        }
        __builtin_amdgcn_s_barrier();
        __builtin_amdgcn_sched_barrier(0);
        if (it + 2 < 16) stage(cur, it + 2);
    }

    #pragma unroll
    for (int ii = 0; ii < 2; ++ii) {
        int r0 = mBase + wr * 32 + ii * 16 + l4 * 4;
        #pragma unroll
        for (int jn = 0; jn < 2; ++jn) {
            int col = nBase + wc * 32 + jn * 16 + l15;
            float bv = bias[col];
            #pragma unroll
            for (int q = 0; q < 4; ++q)
                out[(size_t)(r0 + q) * E_DIM + col] = acc[ii][jn][q] + bv;
        }
    }
}

// ---------------------------------------------------------------------------
extern "C" void kernel_launch(void* const* d_in, const int* in_sizes, int n_in,
                              void* d_out, int out_size, void* d_ws, size_t ws_size,
                              hipStream_t stream)
{
    const float* q_in  = (const float*)d_in[0];
    const float* k_in  = (const float*)d_in[1];
    const float* v_in  = (const float*)d_in[2];
    const float* w_in  = (const float*)d_in[3];
    const float* b_in  = (const float*)d_in[4];
    const float* w_out = (const float*)d_in[5];
    const float* b_out = (const float*)d_in[6];

    // ws layout (40 MiB):
    //   [ 0,12M) xbf bf16 [xq|xk|xv]     [12M,18M) Wibf bf16
    //   [18M,20M) Wobf bf16
    //   [20M,24M) qslab bf16 [b][t][e]   [24M,28M) kslab bf16 [b][t][e]
    //   [28M,32M) ktb bf16 [b][e][t]     [32M,36M) vtb bf16 [b][e][t]
    //   [36M,40M) attnbf bf16 [b][t][e]
    char* w = (char*)d_ws;
    unsigned short* xbf    = (unsigned short*)w;
    unsigned short* Wibf   = (unsigned short*)(w + 12582912);
    unsigned short* Wobf   = (unsigned short*)(w + 18874368);
    unsigned short* qslab  = (unsigned short*)(w + 20971520);
    unsigned short* kslab  = (unsigned short*)(w + 25165824);
    unsigned short* ktb    = (unsigned short*)(w + 29360128);
    unsigned short* vtb    = (unsigned short*)(w + 33554432);
    unsigned short* attnbf = (unsigned short*)(w + 37748736);
    float* outp = (float*)d_out;

    k_cast<<<1280, 256, 0, stream>>>(q_in, k_in, v_in, w_in, w_out, xbf);
    k_gin<<<384, 256, 0, stream>>>(xbf, Wibf, b_in, qslab, kslab, ktb, vtb);
    k_attn<<<512, 256, 0, stream>>>(qslab, kslab, ktb, vtb, attnbf);
    k_gout<<<512, 256, 0, stream>>>(attnbf, Wobf, b_out, outp);
}

// Round 12
// 135.967 us; speedup vs baseline: 1.1436x; 1.0434x over previous
//
#include <hip/hip_runtime.h>

// Round 12: gin retiled 64x256 -> 64x128 (LDS 80KB -> 48KB => 3 blocks/CU,
// grid 768, 12 waves/CU) to restore TLP — round-11 counters showed gin
// latency-bound at Occupancy 14% (1.5 blocks/CU, ~1 wave/SIMD: nothing to
// hide stalls with). Counted-vmcnt 2-deep kept (stage = 6 vm-ops -> WAIT_VM(6)).
// cast / attn / gout byte-identical to round 11.

#define E_DIM 1024

typedef short bf16x8 __attribute__((ext_vector_type(8)));
typedef float f32x4  __attribute__((ext_vector_type(4)));

__device__ inline unsigned short f2bf(float f) {
    unsigned u = __builtin_bit_cast(unsigned, f);
    u = (u + 0x7FFFu + ((u >> 16) & 1u)) >> 16;   // RNE; inputs finite
    return (unsigned short)u;
}

__device__ inline void gload_lds16(const void* g, void* l) {
    __builtin_amdgcn_global_load_lds(
        (const __attribute__((address_space(1))) unsigned int*)g,
        (__attribute__((address_space(3))) unsigned int*)l, 16, 0, 0);
}

// XOR swizzle within each 8-row stripe of a 128B-stride tile (involution).
__device__ inline int swzb(int row, int colbyte) {
    return colbyte ^ ((row & 7) << 4);
}

#define WAIT_VM(N) do { \
    asm volatile("s_waitcnt vmcnt(" #N ")" ::: "memory"); \
    __builtin_amdgcn_sched_barrier(0); } while (0)

// ---------------------------------------------------------------------------
// Kernel 0: cast everything to bf16, contiguous dst:
//   [xq 2M][xk 2M][xv 2M][Wi 3M][Wo 1M] elements.
// ---------------------------------------------------------------------------
__global__ __launch_bounds__(256) void k_cast(
    const float* __restrict__ q_in, const float* __restrict__ k_in,
    const float* __restrict__ v_in, const float* __restrict__ w_in,
    const float* __restrict__ w_out, unsigned short* __restrict__ dst)
{
    #pragma unroll
    for (int l = 0; l < 4; ++l) {
        int id8 = blockIdx.x * 256 + threadIdx.x + l * 327680;
        const float* src;
        if (id8 < 262144)        src = q_in  + (size_t)id8 * 8;
        else if (id8 < 524288)   src = k_in  + (size_t)(id8 - 262144) * 8;
        else if (id8 < 786432)   src = v_in  + (size_t)(id8 - 524288) * 8;
        else if (id8 < 1179648)  src = w_in  + (size_t)(id8 - 786432) * 8;
        else                     src = w_out + (size_t)(id8 - 1179648) * 8;
        float4 f0 = *reinterpret_cast<const float4*>(src);
        float4 f1 = *reinterpret_cast<const float4*>(src + 4);
        ushort4 o0, o1;
        o0.x = f2bf(f0.x); o0.y = f2bf(f0.y); o0.z = f2bf(f0.z); o0.w = f2bf(f0.w);
        o1.x = f2bf(f1.x); o1.y = f2bf(f1.y); o1.z = f2bf(f1.z); o1.w = f2bf(f1.w);
        *reinterpret_cast<ushort4*>(dst + (size_t)id8 * 8)     = o0;
        *reinterpret_cast<ushort4*>(dst + (size_t)id8 * 8 + 4) = o1;
    }
}

// ---------------------------------------------------------------------------
// Kernel 1: in-projection GEMM, 64x128 tile, BK=64, counted-vmcnt 2-deep,
// LDS 48 KB -> 3 blocks/CU. Grid 768 (8 XCD x 96), x-inner chunking.
// Stage = 6 gload_lds/thread (B 4 + A 2).
// Epilogue: z=0 Q natural; z=1 K natural + Kt; z=2 Vt only.
// ---------------------------------------------------------------------------
__global__ __launch_bounds__(256) void k_gin(
    const unsigned short* __restrict__ xbf, const unsigned short* __restrict__ Wibf,
    const float* __restrict__ b_in,
    unsigned short* __restrict__ qslab, unsigned short* __restrict__ kslab,
    unsigned short* __restrict__ ktb,   unsigned short* __restrict__ vtb)
{
    const int i = blockIdx.x;
    const int tile = (i & 7) * 96 + (i >> 3);     // XCD k owns tiles k*96..k*96+95
    const int z = tile >> 8;                      // 256 tiles per z
    const int r = tile & 255;
    const int y = r >> 3, x = r & 7;              // x-inner: 8 n-tiles share A row-tile

    const unsigned short* X = xbf + (size_t)z * 2097152;
    const unsigned short* W = Wibf + (size_t)z * 1048576;
    const float* bz = b_in + z * E_DIM;

    const int nBase = x * 128;
    const int mBase = y * 64;                     // b-major row space
    const int b = mBase >> 10, tBase = mBase & 1023;

    __shared__ short As[2][64 * 64];              // 2 x 8 KB
    __shared__ short Bs[2][128 * 64];             // 2 x 16 KB  (48 KB total)

    const int tid = threadIdx.x;
    const int lane = tid & 63, wave = tid >> 6;
    const int wr = wave >> 1, wc = wave & 1;
    const int l15 = lane & 15, l4 = lane >> 4;

    auto stage = [&](int bufI, int it) {
        int k0 = it * 64;
        #pragma unroll
        for (int l = 0; l < 4; ++l) {             // B: 128x64 bf16 = 16 KB
            int off = l * 4096 + tid * 16;
            int row = off >> 7, cb = off & 127;
            gload_lds16((const char*)W + ((size_t)(nBase + row) * E_DIM + k0) * 2
                            + swzb(row, cb),
                        (char*)&Bs[bufI][0] + off);
        }
        #pragma unroll
        for (int l = 0; l < 2; ++l) {             // A: 64x64 bf16 = 8 KB
            int off = l * 4096 + tid * 16;
            int row = off >> 7, cb = off & 127;
            gload_lds16((const char*)X +
                            ((size_t)((tBase + row) * 2 + b) * E_DIM + k0) * 2
                            + swzb(row, cb),
                        (char*)&As[bufI][0] + off);
        }
    };

    f32x4 acc[2][4] = {};

    stage(0, 0);
    stage(1, 1);
    for (int it = 0; it < 16; ++it) {
        if (it < 15) WAIT_VM(6); else WAIT_VM(0);    // tile it landed (mine)
        __builtin_amdgcn_s_barrier();                // ...and everyone's
        const int cur = it & 1;
        #pragma unroll
        for (int kk = 0; kk < 64; kk += 32) {
            bf16x8 af[2], bfr[4];
            #pragma unroll
            for (int ii = 0; ii < 2; ++ii) {
                int row = wr * 32 + ii * 16 + l15;
                af[ii] = *reinterpret_cast<const bf16x8*>(
                    &As[cur][row * 64 + (swzb(row, (kk + l4 * 8) * 2) >> 1)]);
            }
            #pragma unroll
            for (int jn = 0; jn < 4; ++jn) {
                int row = wc * 64 + jn * 16 + l15;
                bfr[jn] = *reinterpret_cast<const bf16x8*>(
                    &Bs[cur][row * 64 + (swzb(row, (kk + l4 * 8) * 2) >> 1)]);
            }
            #pragma unroll
            for (int ii = 0; ii < 2; ++ii)
                #pragma unroll
                for (int jn = 0; jn < 4; ++jn)
                    acc[ii][jn] = __builtin_amdgcn_mfma_f32_16x16x32_bf16(
                        af[ii], bfr[jn], acc[ii][jn], 0, 0, 0);
        }
        __builtin_amdgcn_s_barrier();                // all reads of cur done
        __builtin_amdgcn_sched_barrier(0);
        if (it + 2 < 16) stage(cur, it + 2);         // refill freed buffer
    }

    #pragma unroll
    for (int ii = 0; ii < 2; ++ii) {
        int t0 = tBase + wr * 32 + ii * 16 + l4 * 4;
        #pragma unroll
        for (int jn = 0; jn < 4; ++jn) {
            int col = nBase + wc * 64 + jn * 16 + l15;
            float bv = bz[col];
            unsigned short v4[4];
            #pragma unroll
            for (int q = 0; q < 4; ++q) v4[q] = f2bf(acc[ii][jn][q] + bv);
            if (z == 0) {
                #pragma unroll
                for (int q = 0; q < 4; ++q)
                    qslab[(size_t)b * 1048576 + (size_t)(t0 + q) * E_DIM + col] = v4[q];
            } else if (z == 1) {
                #pragma unroll
                for (int q = 0; q < 4; ++q)
                    kslab[(size_t)b * 1048576 + (size_t)(t0 + q) * E_DIM + col] = v4[q];
                ushort4 w = {v4[0], v4[1], v4[2], v4[3]};
                *reinterpret_cast<ushort4*>(
                    &ktb[((size_t)b * 1024 + col) * 1024 + t0]) = w;
            } else {
                ushort4 w = {v4[0], v4[1], v4[2], v4[3]};
                *reinterpret_cast<ushort4*>(
                    &vtb[((size_t)b * 1024 + col) * 1024 + t0]) = w;
            }
        }
    }
}

// ---------------------------------------------------------------------------
// Kernel 2: chunked-prefix linear attention, counted-vmcnt 2-deep P-loop.
// Tiles tau = 0..qt: tau<qt -> P chunk (Kt,Vt); tau==qt -> diag (K nat, Vt).
// Stage = 4 gload_lds/thread. Grid 512, XCD-chunked, complementary pairing.
// ---------------------------------------------------------------------------
__global__ __launch_bounds__(256) void k_attn(
    const unsigned short* __restrict__ qslab, const unsigned short* __restrict__ kslab,
    const unsigned short* __restrict__ ktb,  const unsigned short* __restrict__ vtb,
    unsigned short* __restrict__ attnbf)
{
    const int i = blockIdx.x;
    const int xcd = i & 7, u = i >> 3;            // u in 0..63
    const int bh = xcd * 4 + (u >> 4);
    const int qtr = u & 15;
    const int qt = ((u >> 5) & 1) ? (15 - qtr) : qtr;
    const int b = bh >> 4, h = bh & 15;
    const int colb = h * 64, t0q = qt * 64;

    __shared__ short Qs[64 * 64];
    __shared__ short KB[2][64 * 64];              // Kt tiles / diag K natural
    __shared__ short VB[2][64 * 64];              // Vt tiles
    __shared__ short Ss[64 * 72];                 // masked S (padded)
    __shared__ short PTs[64 * 72];                // P^T bf16 (padded)

    const int tid = threadIdx.x;
    const int lane = tid & 63, wave = tid >> 6;
    const int wr = wave >> 1, wc = wave & 1;
    const int l15 = lane & 15, l4 = lane >> 4;

    // unified tile stage: tau < qt -> P chunk; tau == qt -> diag
    auto stage = [&](int bufI, int tau) {
        #pragma unroll
        for (int l = 0; l < 2; ++l) {
            int off = l * 4096 + tid * 16;
            int row = off >> 7, cb = off & 127;
            int scb = swzb(row, cb);
            if (tau < qt) {
                size_t trn = ((size_t)(b * 1024 + colb + row)) * 1024 + tau * 64;
                gload_lds16((const char*)ktb + trn * 2 + scb, (char*)&KB[bufI][0] + off);
                gload_lds16((const char*)vtb + trn * 2 + scb, (char*)&VB[bufI][0] + off);
            } else {
                gload_lds16((const char*)kslab +
                                ((size_t)b * 1048576 + (size_t)(t0q + row) * E_DIM + colb) * 2 + scb,
                            (char*)&KB[bufI][0] + off);
                gload_lds16((const char*)vtb +
                                (((size_t)(b * 1024 + colb + row)) * 1024 + t0q) * 2 + scb,
                            (char*)&VB[bufI][0] + off);
            }
        }
    };

    #pragma unroll
    for (int l = 0; l < 2; ++l) {                 // stage Q once (2 ops)
        int off = l * 4096 + tid * 16;
        int row = off >> 7, cb = off & 127;
        gload_lds16((const char*)qslab +
                        ((size_t)b * 1048576 + (size_t)(t0q + row) * E_DIM + colb) * 2
                        + swzb(row, cb),
                    (char*)Qs + off);
    }
    stage(0, 0);
    if (qt >= 1) stage(1, 1);

    f32x4 pacc[2][2] = {};                        // P[dk][dv] fp32

    // P accumulation over tau = 0..qt-1 (counted vmcnt: next tile always in flight)
    for (int tau = 0; tau < qt; ++tau) {
        WAIT_VM(4);                               // tile tau landed (mine)
        __builtin_amdgcn_s_barrier();
        const int cur = tau & 1;
        #pragma unroll
        for (int kk = 0; kk < 64; kk += 32) {
            bf16x8 af[2], bfr[2];
            #pragma unroll
            for (int ii = 0; ii < 2; ++ii) {
                int row = wr * 32 + ii * 16 + l15;     // dk
                af[ii] = *reinterpret_cast<const bf16x8*>(
                    &KB[cur][row * 64 + (swzb(row, (kk + l4 * 8) * 2) >> 1)]);
            }
            #pragma unroll
            for (int jn = 0; jn < 2; ++jn) {
                int row = wc * 32 + jn * 16 + l15;     // dv
                bfr[jn] = *reinterpret_cast<const bf16x8*>(
                    &VB[cur][row * 64 + (swzb(row, (kk + l4 * 8) * 2) >> 1)]);
            }
            #pragma unroll
            for (int ii = 0; ii < 2; ++ii)
                #pragma unroll
                for (int jn = 0; jn < 2; ++jn)
                    pacc[ii][jn] = __builtin_amdgcn_mfma_f32_16x16x32_bf16(
                        af[ii], bfr[jn], pacc[ii][jn], 0, 0, 0);
        }
        __builtin_amdgcn_s_barrier();
        __builtin_amdgcn_sched_barrier(0);
        if (tau + 2 <= qt) stage(cur, tau + 2);
    }

    // diag tile (tau = qt) in buf[qt&1]
    WAIT_VM(0);
    __builtin_amdgcn_s_barrier();
    const int dcur = qt & 1;

    f32x4 sacc[2][2] = {};
    #pragma unroll
    for (int kk = 0; kk < 64; kk += 32) {
        bf16x8 af[2], bfr[2];
        #pragma unroll
        for (int ii = 0; ii < 2; ++ii) {
            int row = wr * 32 + ii * 16 + l15;         // t
            af[ii] = *reinterpret_cast<const bf16x8*>(
                &Qs[row * 64 + (swzb(row, (kk + l4 * 8) * 2) >> 1)]);
        }
        #pragma unroll
        for (int jn = 0; jn < 2; ++jn) {
            int row = wc * 32 + jn * 16 + l15;         // tk
            bfr[jn] = *reinterpret_cast<const bf16x8*>(
                &KB[dcur][row * 64 + (swzb(row, (kk + l4 * 8) * 2) >> 1)]);
        }
        #pragma unroll
        for (int ii = 0; ii < 2; ++ii)
            #pragma unroll
            for (int jn = 0; jn < 2; ++jn)
                sacc[ii][jn] = __builtin_amdgcn_mfma_f32_16x16x32_bf16(
                    af[ii], bfr[jn], sacc[ii][jn], 0, 0, 0);
    }

    // write P^T (bf16) and masked S to LDS
    #pragma unroll
    for (int ii = 0; ii < 2; ++ii) {
        #pragma unroll
        for (int jn = 0; jn < 2; ++jn) {
            int dv = wc * 32 + jn * 16 + l15;
            int dkb = wr * 32 + ii * 16 + l4 * 4;
            ushort4 pw;
            pw.x = f2bf(pacc[ii][jn][0]); pw.y = f2bf(pacc[ii][jn][1]);
            pw.z = f2bf(pacc[ii][jn][2]); pw.w = f2bf(pacc[ii][jn][3]);
            *reinterpret_cast<ushort4*>(&PTs[dv * 72 + dkb]) = pw;
            int kr = dv;
            #pragma unroll
            for (int q = 0; q < 4; ++q) {
                int qr = dkb + q;
                Ss[qr * 72 + kr] = (kr <= qr) ? (short)f2bf(sacc[ii][jn][q]) : (short)0;
            }
        }
    }
    __syncthreads();

    // O = S @ Vqt + Q @ P
    f32x4 oacc[2][2] = {};
    #pragma unroll
    for (int kk = 0; kk < 64; kk += 32) {
        bf16x8 af[2], bfr[2];
        #pragma unroll
        for (int ii = 0; ii < 2; ++ii)
            af[ii] = *reinterpret_cast<const bf16x8*>(
                        &Ss[(wr * 32 + ii * 16 + l15) * 72 + kk + l4 * 8]);
        #pragma unroll
        for (int jn = 0; jn < 2; ++jn) {
            int row = wc * 32 + jn * 16 + l15;         // dv
            bfr[jn] = *reinterpret_cast<const bf16x8*>(
                &VB[dcur][row * 64 + (swzb(row, (kk + l4 * 8) * 2) >> 1)]);
        }
        #pragma unroll
        for (int ii = 0; ii < 2; ++ii)
            #pragma unroll
            for (int jn = 0; jn < 2; ++jn)
                oacc[ii][jn] = __builtin_amdgcn_mfma_f32_16x16x32_bf16(
                    af[ii], bfr[jn], oacc[ii][jn], 0, 0, 0);
    }
    #pragma unroll
    for (int kk = 0; kk < 64; kk += 32) {
        bf16x8 af[2], bfr[2];
        #pragma unroll
        for (int ii = 0; ii < 2; ++ii) {
            int row = wr * 32 + ii * 16 + l15;         // t
            af[ii] = *reinterpret_cast<const bf16x8*>(
                &Qs[row * 64 + (swzb(row, (kk + l4 * 8) * 2) >> 1)]);
        }
        #pragma unroll
        for (int jn = 0; jn < 2; ++jn)
            bfr[jn] = *reinterpret_cast<const bf16x8*>(
                        &PTs[(wc * 32 + jn * 16 + l15) * 72 + kk + l4 * 8]);
        #pragma unroll
        for (int ii = 0; ii < 2; ++ii)
            #pragma unroll
            for (int jn = 0; jn < 2; ++jn)
                oacc[ii][jn] = __builtin_amdgcn_mfma_f32_16x16x32_bf16(
                    af[ii], bfr[jn], oacc[ii][jn], 0, 0, 0);
    }

    #pragma unroll
    for (int ii = 0; ii < 2; ++ii) {
        #pragma unroll
        for (int jn = 0; jn < 2; ++jn) {
            int dv = wc * 32 + jn * 16 + l15;
            #pragma unroll
            for (int q = 0; q < 4; ++q) {
                int qr = wr * 32 + ii * 16 + l4 * 4 + q;
                attnbf[(size_t)b * 1048576 + (size_t)(t0q + qr) * E_DIM + colb + dv] =
                    f2bf(oacc[ii][jn][q] * 0.125f);
            }
        }
    }
}

// ---------------------------------------------------------------------------
// Kernel 3: out-projection GEMM, 64x64 tile, counted-vmcnt 2-deep.
// Stage = 4 gload_lds/thread. Grid 512 XCD-chunked. fp32 out rows r = t*2+b.
// ---------------------------------------------------------------------------
__global__ __launch_bounds__(256) void k_gout(
    const unsigned short* __restrict__ attnbf, const unsigned short* __restrict__ Wobf,
    const float* __restrict__ bias, float* __restrict__ out)
{
    const int i = blockIdx.x;
    const int tile = (i & 7) * 64 + (i >> 3);     // 512 = 8 * 64
    const int x = tile & 15, y = tile >> 4;
    const int nBase = x * 64;
    const int mBase = y * 64;                     // r-space (t*2+b)

    __shared__ short As[2][64 * 64];
    __shared__ short Bs[2][64 * 64];

    const int tid = threadIdx.x;
    const int lane = tid & 63, wave = tid >> 6;
    const int wr = wave >> 1, wc = wave & 1;
    const int l15 = lane & 15, l4 = lane >> 4;

    auto stage = [&](int bufI, int it) {
        int k0 = it * 64;
        #pragma unroll
        for (int l = 0; l < 2; ++l) {
            int off = l * 4096 + tid * 16;
            int row = off >> 7, cb = off & 127;
            int scb = swzb(row, cb);
            gload_lds16((const char*)Wobf + ((size_t)(nBase + row) * E_DIM + k0) * 2 + scb,
                        (char*)&Bs[bufI][0] + off);
            int r = mBase + row, t = r >> 1, bb = r & 1;
            gload_lds16((const char*)attnbf +
                            ((size_t)bb * 1048576 + (size_t)t * E_DIM + k0) * 2 + scb,
                        (char*)&As[bufI][0] + off);
        }
    };

    f32x4 acc[2][2] = {};

    stage(0, 0);
    stage(1, 1);
    for (int it = 0; it < 16; ++it) {
        if (it < 15) WAIT_VM(4); else WAIT_VM(0);
        __builtin_amdgcn_s_barrier();
        const int cur = it & 1;
        #pragma unroll
        for (int kk = 0; kk < 64; kk += 32) {
            bf16x8 af[2], bfr[2];
            #pragma unroll
            for (int ii = 0; ii < 2; ++ii) {
                int row = wr * 32 + ii * 16 + l15;
                af[ii] = *reinterpret_cast<const bf16x8*>(
                    &As[cur][row * 64 + (swzb(row, (kk + l4 * 8) * 2) >> 1)]);
            }
            #pragma unroll
            for (int jn = 0; jn < 2; ++jn) {
                int row = wc * 32 + jn * 16 + l15;
                bfr[jn] = *reinterpret_cast<const bf16x8*>(
                    &Bs[cur][row * 64 + (swzb(row, (kk + l4 * 8) * 2) >> 1)]);
            }
            #pragma unroll
            for (int ii = 0; ii < 2; ++ii)
                #pragma unroll
                for (int jn = 0; jn < 2; ++jn)
                    acc[ii][jn] = __builtin_amdgcn_mfma_f32_16x16x32_bf16(
                        af[ii], bfr[jn], acc[ii][jn], 0, 0, 0);
        }
        __builtin_amdgcn_s_barrier();
        __builtin_amdgcn_sched_barrier(0);
        if (it + 2 < 16) stage(cur, it + 2);
    }

    #pragma unroll
    for (int ii = 0; ii < 2; ++ii) {
        int r0 = mBase + wr * 32 + ii * 16 + l4 * 4;
        #pragma unroll
        for (int jn = 0; jn < 2; ++jn) {
            int col = nBase + wc * 32 + jn * 16 + l15;
            float bv = bias[col];
            #pragma unroll
            for (int q = 0; q < 4; ++q)
                out[(size_t)(r0 + q) * E_DIM + col] = acc[ii][jn][q] + bv;
        }
    }
}

// ---------------------------------------------------------------------------
extern "C" void kernel_launch(void* const* d_in, const int* in_sizes, int n_in,
                              void* d_out, int out_size, void* d_ws, size_t ws_size,
                              hipStream_t stream)
{
    const float* q_in  = (const float*)d_in[0];
    const float* k_in  = (const float*)d_in[1];
    const float* v_in  = (const float*)d_in[2];
    const float* w_in  = (const float*)d_in[3];
    const float* b_in  = (const float*)d_in[4];
    const float* w_out = (const float*)d_in[5];
    const float* b_out = (const float*)d_in[6];

    // ws layout (40 MiB):
    //   [ 0,12M) xbf bf16 [xq|xk|xv]     [12M,18M) Wibf bf16
    //   [18M,20M) Wobf bf16
    //   [20M,24M) qslab bf16 [b][t][e]   [24M,28M) kslab bf16 [b][t][e]
    //   [28M,32M) ktb bf16 [b][e][t]     [32M,36M) vtb bf16 [b][e][t]
    //   [36M,40M) attnbf bf16 [b][t][e]
    char* w = (char*)d_ws;
    unsigned short* xbf    = (unsigned short*)w;
    unsigned short* Wibf   = (unsigned short*)(w + 12582912);
    unsigned short* Wobf   = (unsigned short*)(w + 18874368);
    unsigned short* qslab  = (unsigned short*)(w + 20971520);
    unsigned short* kslab  = (unsigned short*)(w + 25165824);
    unsigned short* ktb    = (unsigned short*)(w + 29360128);
    unsigned short* vtb    = (unsigned short*)(w + 33554432);
    unsigned short* attnbf = (unsigned short*)(w + 37748736);
    float* outp = (float*)d_out;

    k_cast<<<1280, 256, 0, stream>>>(q_in, k_in, v_in, w_in, w_out, xbf);
    k_gin<<<768, 256, 0, stream>>>(xbf, Wibf, b_in, qslab, kslab, ktb, vtb);
    k_attn<<<512, 256, 0, stream>>>(qslab, kslab, ktb, vtb, attnbf);
    k_gout<<<512, 256, 0, stream>>>(attnbf, Wobf, b_out, outp);
}